// Round 4
// baseline (3387.026 us; speedup 1.0000x reference)
//
#include <hip/hip_runtime.h>
#include <hip/hip_bf16.h>
#include <stdint.h>

typedef __attribute__((ext_vector_type(8))) short short8;
typedef __attribute__((ext_vector_type(4))) float f32x4;

#define NEL 1601978   // 1778*901
#define NROWS 1778
#define OUTF 901

__device__ __forceinline__ float b2f(__hip_bfloat16 x) { return __bfloat162float(x); }
__device__ __forceinline__ __hip_bfloat16 f2b(float x) { return __float2bfloat16(x); }
__device__ __forceinline__ float sane(float v) { return isfinite(v) ? v : 0.f; }

// dtype-dual load: flag==1 -> fp32 array, flag==0 -> bf16 array
__device__ __forceinline__ float ldf(const void* p, long i, int f32)
{
    return f32 ? ((const float*)p)[i] : b2f(((const __hip_bfloat16*)p)[i]);
}

// ---------------- dtype probe ----------------
// a_src_drug has scale 0.02: every genuine bf16 value has |x| < 0.2.
// If the buffer is fp32, odd ushorts are mantissa junk: ~48% decode to
// |bf16| >= 64 (biased exponent >= 0x85) or NaN/Inf. Count them.
__global__ void probe_dtype(const ushort* __restrict__ p, int* __restrict__ fdt)
{
    int t = threadIdx.x;
    int cnt = 0;
    for (int i = t; i < 512; i += 256) {
        int ex = (p[i] >> 7) & 0xFF;
        if (ex >= 0x85) cnt++;
    }
    for (int o = 32; o; o >>= 1) cnt += __shfl_down(cnt, o);
    __shared__ int s[4];
    if ((t & 63) == 0) s[t >> 6] = cnt;
    __syncthreads();
    if (t == 0) fdt[0] = (s[0] + s[1] + s[2] + s[3] > 16) ? 1 : 0;
}

// ---------------- zero scratch ----------------
__global__ void zerof(float* __restrict__ p, int n)
{
    int i = blockIdx.x * 256 + threadIdx.x;
    if (i < n) p[i] = 0.f;
}

// ---------------- GEMM1: hT = W · feat^T, raw operands, dtype-dual ----------------
// A = W [Ma x Kv] stride lda, B = feat [Nb x Kv] stride ldb, both raw d_in.
// K = Kv rounded to 64. C bf16 [grid_y*128 x grid_x*128] stride ldc.
__global__ __launch_bounds__(256)
void gemm1_raw(const void* __restrict__ A, const void* __restrict__ B, int K,
               int lda, int ldb, int Ma, int Nb, int Kv,
               __hip_bfloat16* __restrict__ Cbf, int ldc, const int* __restrict__ fdt)
{
    __shared__ __align__(16) ushort sA[128 * 64];
    __shared__ __align__(16) ushort sB[128 * 64];
    const int f32 = fdt[0];
    const int tid = threadIdx.x;
    const int lane = tid & 63;
    const int wid = tid >> 6;
    const int wm = (wid >> 1) * 64;
    const int wn = (wid & 1) * 64;
    const long m0 = (long)blockIdx.y * 128;
    const long n0 = (long)blockIdx.x * 128;

    f32x4 acc[4][4];
#pragma unroll
    for (int i = 0; i < 4; ++i)
#pragma unroll
        for (int j = 0; j < 4; ++j) acc[i][j] = (f32x4){0.f, 0.f, 0.f, 0.f};

    const int lr = tid >> 3;          // 0..31
    const int lc = (tid & 7) * 8;     // element col offset
    const int koff = (lane >> 4) * 8;
    const int rowf = lane & 15;

    for (int k0 = 0; k0 < K; k0 += 64) {
        __syncthreads();
#pragma unroll
        for (int it = 0; it < 4; ++it) {
            int r = it * 32 + lr;
            long gm = m0 + r, gn = n0 + r;
            ushort va[8], vb[8];
#pragma unroll
            for (int e = 0; e < 8; ++e) {
                int k = k0 + lc + e;
                bool kok = (k < Kv);
                float fa = (kok && gm < Ma) ? ldf(A, gm * (long)lda + k, f32) : 0.f;
                float fb = (kok && gn < Nb) ? ldf(B, gn * (long)ldb + k, f32) : 0.f;
                va[e] = __hip_bfloat16_raw(f2b(fa)).x;
                vb[e] = __hip_bfloat16_raw(f2b(fb)).x;
            }
#pragma unroll
            for (int e = 0; e < 8; ++e) { sA[r * 64 + lc + e] = va[e]; sB[r * 64 + lc + e] = vb[e]; }
        }
        __syncthreads();
#pragma unroll
        for (int ks = 0; ks < 64; ks += 32) {
            short8 af[4], bfr[4];
            int kb = ks + koff;
#pragma unroll
            for (int f = 0; f < 4; ++f) {
                af[f]  = *(const short8*)(&sA[(wm + f * 16 + rowf) * 64 + kb]);
                bfr[f] = *(const short8*)(&sB[(wn + f * 16 + rowf) * 64 + kb]);
            }
#pragma unroll
            for (int i = 0; i < 4; ++i)
#pragma unroll
                for (int j = 0; j < 4; ++j)
                    acc[i][j] = __builtin_amdgcn_mfma_f32_16x16x32_bf16(af[i], bfr[j], acc[i][j], 0, 0, 0);
        }
    }

    const int rq = (lane >> 4) * 4;   // C/D: col = lane&15, row = (lane>>4)*4 + reg
#pragma unroll
    for (int i = 0; i < 4; ++i)
#pragma unroll
        for (int j = 0; j < 4; ++j)
#pragma unroll
            for (int rg = 0; rg < 4; ++rg) {
                long m = m0 + wm + i * 16 + rq + rg;
                long n = n0 + wn + j * 16 + (lane & 15);
                Cbf[m * ldc + n] = f2b(acc[i][j][rg]);
            }
}

// ---------------- GEMM2: vout = relu(P·h / l + bias), padded bf16 operands ----------------
__global__ __launch_bounds__(256)
void gemm2_epi(const ushort* __restrict__ A, const ushort* __restrict__ B, int K,
               const float* __restrict__ lrow, const void* __restrict__ bias,
               __hip_bfloat16* __restrict__ vout, int Mvalid, int Nvalid,
               const int* __restrict__ fdt)
{
    __shared__ __align__(16) ushort sA[128 * 64];
    __shared__ __align__(16) ushort sB[128 * 64];
    const int tid = threadIdx.x;
    const int lane = tid & 63;
    const int wid = tid >> 6;
    const int wm = (wid >> 1) * 64;
    const int wn = (wid & 1) * 64;
    const long m0 = (long)blockIdx.y * 128;
    const long n0 = (long)blockIdx.x * 128;

    f32x4 acc[4][4];
#pragma unroll
    for (int i = 0; i < 4; ++i)
#pragma unroll
        for (int j = 0; j < 4; ++j) acc[i][j] = (f32x4){0.f, 0.f, 0.f, 0.f};

    const int lr = tid >> 3;
    const int lc = (tid & 7) * 8;
    const int koff = (lane >> 4) * 8;
    const int rowf = lane & 15;

    for (int k0 = 0; k0 < K; k0 += 64) {
        __syncthreads();
#pragma unroll
        for (int it = 0; it < 4; ++it) {
            int r = it * 32 + lr;
            *(uint4*)(&sA[r * 64 + lc]) = *(const uint4*)(A + (m0 + r) * (long)K + k0 + lc);
            *(uint4*)(&sB[r * 64 + lc]) = *(const uint4*)(B + (n0 + r) * (long)K + k0 + lc);
        }
        __syncthreads();
#pragma unroll
        for (int ks = 0; ks < 64; ks += 32) {
            short8 af[4], bfr[4];
            int kb = ks + koff;
#pragma unroll
            for (int f = 0; f < 4; ++f) {
                af[f]  = *(const short8*)(&sA[(wm + f * 16 + rowf) * 64 + kb]);
                bfr[f] = *(const short8*)(&sB[(wn + f * 16 + rowf) * 64 + kb]);
            }
#pragma unroll
            for (int i = 0; i < 4; ++i)
#pragma unroll
                for (int j = 0; j < 4; ++j)
                    acc[i][j] = __builtin_amdgcn_mfma_f32_16x16x32_bf16(af[i], bfr[j], acc[i][j], 0, 0, 0);
        }
    }

    const int f32 = fdt[0];
    const int rq = (lane >> 4) * 4;
#pragma unroll
    for (int i = 0; i < 4; ++i)
#pragma unroll
        for (int j = 0; j < 4; ++j)
#pragma unroll
            for (int rg = 0; rg < 4; ++rg) {
                long m = m0 + wm + i * 16 + rq + rg;
                long n = n0 + wn + j * 16 + (lane & 15);
                if (m < Mvalid && n < Nvalid) {
                    float den = fmaxf(lrow[m], 1e-30f);
                    float r = acc[i][j][rg] / den + ldf(bias, n, f32);
                    vout[m * Nvalid + n] = f2b(sane(fmaxf(r, 0.f)));
                }
            }
}

// ---------------- asrc[j] = h[j,:]·a_src, adst[j] = h[j,:]·a_dst ----------------
__global__ void srcdst(const __hip_bfloat16* __restrict__ hT,
                       const void* __restrict__ a_src, const void* __restrict__ a_dst,
                       int Nv, int Nvp, float* __restrict__ asrc, float* __restrict__ adst,
                       const int* __restrict__ fdt)
{
    __shared__ float as[OUTF], ad[OUTF];
    const int f32 = fdt[0];
    int tid = threadIdx.x;
    for (int k = tid; k < OUTF; k += 256) { as[k] = ldf(a_src, k, f32); ad[k] = ldf(a_dst, k, f32); }
    __syncthreads();
    int j = blockIdx.x * 256 + tid;
    if (j >= Nv) return;
    float s1 = 0.f, s2 = 0.f;
    for (int o = 0; o < OUTF; ++o) {
        float hv = b2f(hT[(long)o * Nvp + j]);
        s1 += hv * as[o];
        s2 += hv * ad[o];
    }
    asrc[j] = s1;
    adst[j] = s2;
}

// ---------------- P = mask * exp(leaky(adst_i + asrc_j)), row sums l ----------------
__global__ void pbuild(const int* __restrict__ adj, const float* __restrict__ asrc,
                       const float* __restrict__ adst, int Nv, int Nvp, int ioff,
                       __hip_bfloat16* __restrict__ P, float* __restrict__ l)
{
    const int lane = threadIdx.x & 63, grp = threadIdx.x >> 6;
    const int j0 = blockIdx.x * 64, r0 = blockIdx.y * 64;
    const int j = j0 + lane;
    const float as = (j < Nv) ? asrc[j] : 0.f;
#pragma unroll
    for (int it = 0; it < 16; ++it) {
        int rr = it * 4 + grp;
        int r = r0 + rr;
        int i = (r < 901) ? r : r + ioff;
        float p = 0.f;
        if (r < NROWS && j < Nv) {
            bool m = (adj[(long)j * Nv + i] != 0) || (i == j);
            if (m) {
                float e = adst[i] + as;
                e = e > 0.f ? e : 0.2f * e;
                p = expf(fminf(e, 30.f));
            }
        }
        __hip_bfloat16 pb = f2b(p);
        if (r < 1792) P[(long)r * Nvp + j] = pb;
        float pv = b2f(pb);
        for (int o = 32; o; o >>= 1) pv += __shfl_down(pv, o);
        if (lane == 0 && r < NROWS) atomicAdd(&l[r], pv);
    }
}

// ---------------- CAM ----------------
__device__ __forceinline__ void block_reduce_atomic4(float a, float b, float c, float d, double* out)
{
    for (int o = 32; o; o >>= 1) {
        a += __shfl_down(a, o); b += __shfl_down(b, o);
        c += __shfl_down(c, o); d += __shfl_down(d, o);
    }
    __shared__ float s[4][4];
    int lane = threadIdx.x & 63, wv = threadIdx.x >> 6;
    if (lane == 0) { s[wv][0] = a; s[wv][1] = b; s[wv][2] = c; s[wv][3] = d; }
    __syncthreads();
    if (threadIdx.x < 4) {
        float v = s[0][threadIdx.x] + s[1][threadIdx.x] + s[2][threadIdx.x] + s[3][threadIdx.x];
        atomicAdd(out + threadIdx.x, (double)v);
    }
}

// recompute Yl,Yg for element idx from the four channel views
__device__ __forceinline__ void camY(int idx,
    const __hip_bfloat16* v0, const __hip_bfloat16* v1, const __hip_bfloat16* v2,
    const void* md, const void* lw1, const void* lb1, const void* gw1, const void* gb1,
    int f32, float& Yl, float& Yg)
{
    float x0 = b2f(v0[idx]), x1 = b2f(v1[idx]), x2 = b2f(v2[idx]), x3 = ldf(md, idx, f32);
    Yl = ldf(lw1,0,f32)*x0 + ldf(lw1,1,f32)*x1 + ldf(lw1,2,f32)*x2 + ldf(lw1,3,f32)*x3 + ldf(lb1,0,f32);
    Yg = ldf(gw1,0,f32)*x0 + ldf(gw1,1,f32)*x1 + ldf(gw1,2,f32)*x2 + ldf(gw1,3,f32)*x3 + ldf(gb1,0,f32);
}

__global__ void cam_pass1(const __hip_bfloat16* __restrict__ v0, const __hip_bfloat16* __restrict__ v1,
                          const __hip_bfloat16* __restrict__ v2, const void* __restrict__ md,
                          const void* __restrict__ lw1, const void* __restrict__ lb1,
                          const void* __restrict__ gw1, const void* __restrict__ gb1,
                          double* __restrict__ sD, const int* __restrict__ fdt)
{
    int idx = blockIdx.x * 256 + threadIdx.x;
    float a = 0, b = 0, c = 0, d = 0;
    if (idx < NEL) {
        float Yl, Yg;
        camY(idx, v0, v1, v2, md, lw1, lb1, gw1, gb1, fdt[0], Yl, Yg);
        a = Yl; b = Yl * Yl; c = Yg; d = Yg * Yg;
    }
    block_reduce_atomic4(a, b, c, d, sD);
}

__global__ void cam_fin1(const double* __restrict__ sD, float* __restrict__ sF)
{
    if (threadIdx.x == 0) {
        double n = (double)NEL;
        double ml = sD[0] / n, vl = sD[1] / n - ml * ml;
        double mg = sD[2] / n, vg = sD[3] / n - mg * mg;
        if (vl < 0.0) vl = 0.0;
        if (vg < 0.0) vg = 0.0;
        sF[0] = (float)ml; sF[1] = (float)(1.0 / sqrt(vl + 1e-5));
        sF[2] = (float)mg; sF[3] = (float)(1.0 / sqrt(vg + 1e-5));
    }
}

__global__ void cam_pass2(const __hip_bfloat16* __restrict__ v0, const __hip_bfloat16* __restrict__ v1,
                          const __hip_bfloat16* __restrict__ v2, const void* __restrict__ md,
                          const void* __restrict__ lw1, const void* __restrict__ lb1,
                          const void* __restrict__ gw1, const void* __restrict__ gb1,
                          const float* __restrict__ sF, double* __restrict__ sD,
                          const int* __restrict__ fdt)
{
    int idx = blockIdx.x * 256 + threadIdx.x;
    float a = 0, b = 0, c = 0, d = 0;
    if (idx < NEL) {
        float Yl, Yg;
        camY(idx, v0, v1, v2, md, lw1, lb1, gw1, gb1, fdt[0], Yl, Yg);
        float zl = fmaxf((Yl - sF[0]) * sF[1], 0.f);
        float zg = fmaxf((Yg - sF[2]) * sF[3], 0.f);
        a = zl; b = zl * zl; c = zg; d = zg * zg;
    }
    block_reduce_atomic4(a, b, c, d, sD + 4);
}

__global__ void cam_fin2(const double* __restrict__ sD, float* __restrict__ sF,
                         const void* __restrict__ lw2, const void* __restrict__ gw2,
                         const int* __restrict__ fdt)
{
    if (threadIdx.x == 0) {
        const int f32 = fdt[0];
        double n = (double)NEL;
        double mzl = sD[4] / n, vzl = sD[5] / n - mzl * mzl;
        double mzg = sD[6] / n, vzg = sD[7] / n - mzg * mzg;
        if (vzl < 0.0) vzl = 0.0;
        if (vzg < 0.0) vzg = 0.0;
        sF[4] = (float)mzl; sF[5] = (float)mzg;
        for (int c = 0; c < 4; ++c) {
            double wl = (double)ldf(lw2, c, f32);
            double wg = (double)ldf(gw2, c, f32);
            sF[6 + c]  = (float)(wl / sqrt(wl * wl * vzl + 1e-5));
            sF[10 + c] = (float)(wg / sqrt(wg * wg * vzg + 1e-5));
        }
    }
}

__global__ void cam_fuse(const __hip_bfloat16* __restrict__ v0, const __hip_bfloat16* __restrict__ v1,
                         const __hip_bfloat16* __restrict__ v2, const void* __restrict__ md,
                         const void* __restrict__ lw1, const void* __restrict__ lb1,
                         const void* __restrict__ gw1, const void* __restrict__ gb1,
                         const float* __restrict__ sF, float* __restrict__ sumx,
                         const int* __restrict__ fdt)
{
    int idx = blockIdx.x * 256 + threadIdx.x;
    if (idx >= NEL) return;
    const int f32 = fdt[0];
    float Yl, Yg;
    camY(idx, v0, v1, v2, md, lw1, lb1, gw1, gb1, f32, Yl, Yg);
    float zl = fmaxf((Yl - sF[0]) * sF[1], 0.f);
    float zg = fmaxf((Yg - sF[2]) * sF[3], 0.f);
    float dzl = zl - sF[4], dzg = zg - sF[5];
    float x[4] = {b2f(v0[idx]), b2f(v1[idx]), b2f(v2[idx]), ldf(md, idx, f32)};
    float s = 0.f;
#pragma unroll
    for (int c = 0; c < 4; ++c) {
        float t = sF[6 + c] * dzl + sF[10 + c] * dzg;
        s += x[c] / (1.f + expf(-t));
    }
    sumx[idx] = 0.25f * s;
}

// ---------------- collapsed MLP head ----------------
__global__ void mlp_head(const void* __restrict__ mW2, const void* __restrict__ mW3,
                         const void* __restrict__ mW4, const void* __restrict__ mb1,
                         const void* __restrict__ mb2, const void* __restrict__ mb3,
                         const void* __restrict__ mb4, float* __restrict__ u1out,
                         float* __restrict__ sF, const int* __restrict__ fdt)
{
    __shared__ float u3[64];
    __shared__ float u2[512];
    __shared__ float u1[1024];
    __shared__ float red[4];
    const int f32 = fdt[0];
    int t = threadIdx.x;
    if (t < 64) u3[t] = ldf(mW4, t, f32);
    __syncthreads();
    for (int k = t; k < 512; k += 256) {
        float s = 0.f;
        for (int o = 0; o < 64; ++o) s += ldf(mW3, o * 512 + k, f32) * u3[o];
        u2[k] = s;
    }
    __syncthreads();
    for (int k = t; k < 1024; k += 256) {
        float s = 0.f;
        for (int o = 0; o < 512; ++o) s += ldf(mW2, o * 1024 + k, f32) * u2[o];
        u1[k] = s;
    }
    __syncthreads();
    float p = 0.f;
    for (int k = t; k < 1024; k += 256) { p += ldf(mb1, k, f32) * u1[k]; u1out[k] = u1[k]; }
    for (int k = t; k < 512; k += 256) p += ldf(mb2, k, f32) * u2[k];
    if (t < 64) p += ldf(mb3, t, f32) * u3[t];
    for (int o = 32; o; o >>= 1) p += __shfl_down(p, o);
    int lane = t & 63, wv = t >> 6;
    if (!lane) red[wv] = p;
    __syncthreads();
    if (t == 0) sF[14] = red[0] + red[1] + red[2] + red[3] + ldf(mb4, 0, f32);
}

__global__ void mlp_u0(const void* __restrict__ mW1, const float* __restrict__ u1,
                       float* __restrict__ u0, const int* __restrict__ fdt)
{
    int k = blockIdx.x * 256 + threadIdx.x;
    if (k >= 1802) return;
    const int f32 = fdt[0];
    float s = 0.f;
    for (int o = 0; o < 1024; ++o) s += ldf(mW1, (long)o * 1802 + k, f32) * u1[o];
    u0[k] = s;
}

__global__ void rowdot(const float* __restrict__ sumx, const float* __restrict__ u0,
                       float* __restrict__ f, float* __restrict__ g)
{
    int r = blockIdx.x, t = threadIdx.x;
    float fa = 0.f, ga = 0.f;
    for (int o = t; o < OUTF; o += 256) {
        float v = sumx[(long)r * OUTF + o];
        fa += v * u0[o];
        ga += v * u0[OUTF + o];
    }
    for (int o = 32; o; o >>= 1) { fa += __shfl_down(fa, o); ga += __shfl_down(ga, o); }
    __shared__ float s[4][2];
    int lane = t & 63, wv = t >> 6;
    if (!lane) { s[wv][0] = fa; s[wv][1] = ga; }
    __syncthreads();
    if (t == 0) {
        f[r] = s[0][0] + s[1][0] + s[2][0] + s[3][0];
        g[r] = s[0][1] + s[1][1] + s[2][1] + s[3][1];
    }
}

__global__ void score(const int* __restrict__ ts, const float* __restrict__ f,
                      const float* __restrict__ g, const float* __restrict__ sF,
                      void* __restrict__ out, const int* __restrict__ fdt)
{
    int p = blockIdx.x * 256 + threadIdx.x;
    if (p >= 4096) return;
    float v = sane(f[ts[2 * p]] + g[ts[2 * p + 1]] + sF[14]);
    if (fdt[0]) ((float*)out)[p] = v;
    else        ((__hip_bfloat16*)out)[p] = f2b(v);
}

// ---------------- launch ----------------
extern "C" void kernel_launch(void* const* d_in, const int* in_sizes, int n_in,
                              void* d_out, int out_size, void* d_ws, size_t ws_size,
                              hipStream_t stream)
{
    const int NVv[3]   = {2060, 2459, 3929};
    const int NVPv[3]  = {2176, 2560, 3968};
    const int IOFFv[3] = {282, 681, 2151};
    const int ADJ_I[3] = {0, 1, 2}, FEAT_I[3] = {4, 5, 6}, W_I[3] = {8, 12, 16},
              AS_I[3] = {9, 13, 17}, AD_I[3] = {10, 14, 18}, BV_I[3] = {11, 15, 19};

    char* w = (char*)d_ws;
    size_t off = 0;
    auto alloc = [&](size_t b) { void* p = w + off; off += (b + 255) & ~(size_t)255; return p; };

    ushort* hT   = (ushort*)alloc(1024ULL * 3968 * 2);            // 8.1 MB
    ushort* Pexp = (ushort*)alloc(1792ULL * 3968 * 2);            // 14.2 MB
    __hip_bfloat16* voutb[3];
    for (int v = 0; v < 3; ++v)
        voutb[v] = (__hip_bfloat16*)alloc((size_t)NROWS * OUTF * 2);  // 3x 3.2 MB
    float*  asrc   = (float*)alloc(3968 * 4);
    float*  adst   = (float*)alloc(3968 * 4);
    float*  lrow   = (float*)alloc(1792 * 4);
    double* statsD = (double*)alloc(8 * 8);
    float*  statsF = (float*)alloc(16 * 4);
    float*  u1     = (float*)alloc(1024 * 4);
    float*  u0     = (float*)alloc(1802 * 4);
    float*  fv     = (float*)alloc(NROWS * 4);
    float*  gv     = (float*)alloc(NROWS * 4);
    int*    fdt    = (int*)alloc(4);
    // sumx overlays hT (dead after the view loop; 6.4 MB < 8.1 MB)
    float* sumx = (float*)hT;

    probe_dtype<<<1, 256, 0, stream>>>((const ushort*)d_in[9], fdt);

    for (int v = 0; v < 3; ++v) {
        int Nv = NVv[v], Nvp = NVPv[v], ioff2 = IOFFv[v];
        int Kp = (Nv + 63) & ~63;

        dim3 gg1(Nvp / 128, 8);   // hT[1024, Nvp] = W · feat^T
        gemm1_raw<<<gg1, 256, 0, stream>>>(d_in[W_I[v]], d_in[FEAT_I[v]], Kp,
                                           Nv, Nv, 901, Nv, Nv,
                                           (__hip_bfloat16*)hT, Nvp, fdt);

        srcdst<<<(Nv + 255) / 256, 256, 0, stream>>>((const __hip_bfloat16*)hT,
            d_in[AS_I[v]], d_in[AD_I[v]], Nv, Nvp, asrc, adst, fdt);

        zerof<<<7, 256, 0, stream>>>(lrow, 1792);
        dim3 gp(Nvp / 64, 28);
        pbuild<<<gp, 256, 0, stream>>>((const int*)d_in[ADJ_I[v]], asrc, adst, Nv, Nvp, ioff2,
                                       (__hip_bfloat16*)Pexp, lrow);

        dim3 gg2(8, 14);          // vout[1778,901] = relu(P·h / l + b)
        gemm2_epi<<<gg2, 256, 0, stream>>>(Pexp, hT, Nvp, lrow, d_in[BV_I[v]],
                                           voutb[v], NROWS, OUTF, fdt);
    }

    zerof<<<1, 256, 0, stream>>>((float*)statsD, 16);
    int gb = (NEL + 255) / 256;
    cam_pass1<<<gb, 256, 0, stream>>>(voutb[0], voutb[1], voutb[2], d_in[7],
        d_in[20], d_in[21], d_in[24], d_in[25], statsD, fdt);
    cam_fin1<<<1, 64, 0, stream>>>(statsD, statsF);
    cam_pass2<<<gb, 256, 0, stream>>>(voutb[0], voutb[1], voutb[2], d_in[7],
        d_in[20], d_in[21], d_in[24], d_in[25], statsF, statsD, fdt);
    cam_fin2<<<1, 64, 0, stream>>>(statsD, statsF, d_in[22], d_in[26], fdt);
    cam_fuse<<<gb, 256, 0, stream>>>(voutb[0], voutb[1], voutb[2], d_in[7],
        d_in[20], d_in[21], d_in[24], d_in[25], statsF, sumx, fdt);

    mlp_head<<<1, 256, 0, stream>>>(d_in[30], d_in[32], d_in[34], d_in[29],
        d_in[31], d_in[33], d_in[35], u1, statsF, fdt);
    mlp_u0<<<8, 256, 0, stream>>>(d_in[28], u1, u0, fdt);
    rowdot<<<NROWS, 256, 0, stream>>>(sumx, u0, fv, gv);
    score<<<16, 256, 0, stream>>>((const int*)d_in[3], fv, gv, statsF, d_out, fdt);
}

// Round 5
// 1868.136 us; speedup vs baseline: 1.8131x; 1.8131x over previous
//
#include <hip/hip_runtime.h>
#include <hip/hip_bf16.h>
#include <stdint.h>

typedef __attribute__((ext_vector_type(8))) short short8;
typedef __attribute__((ext_vector_type(4))) float f32x4;

#define NEL 1601978   // 1778*901
#define NROWS 1778
#define OUTF 901

__device__ __forceinline__ float b2f(__hip_bfloat16 x) { return __bfloat162float(x); }
__device__ __forceinline__ __hip_bfloat16 f2b(float x) { return __float2bfloat16(x); }
__device__ __forceinline__ float sane(float v) { return isfinite(v) ? v : 0.f; }

// dtype-dual load: flag==1 -> fp32 array, flag==0 -> bf16 array
__device__ __forceinline__ float ldf(const void* p, long i, int f32)
{
    return f32 ? ((const float*)p)[i] : b2f(((const __hip_bfloat16*)p)[i]);
}

// ---------------- dtype probe ----------------
__global__ void probe_dtype(const ushort* __restrict__ p, int* __restrict__ fdt)
{
    int t = threadIdx.x;
    int cnt = 0;
    for (int i = t; i < 512; i += 256) {
        int ex = (p[i] >> 7) & 0xFF;
        if (ex >= 0x85) cnt++;
    }
    for (int o = 32; o; o >>= 1) cnt += __shfl_down(cnt, o);
    __shared__ int s[4];
    if ((t & 63) == 0) s[t >> 6] = cnt;
    __syncthreads();
    if (t == 0) fdt[0] = (s[0] + s[1] + s[2] + s[3] > 16) ? 1 : 0;
}

// ---------------- zero scratch ----------------
__global__ void zerof(float* __restrict__ p, int n)
{
    int i = blockIdx.x * 256 + threadIdx.x;
    if (i < n) p[i] = 0.f;
}

// ---------------- pack (fp32|bf16) -> padded bf16 ----------------
__global__ void pack_dual(__hip_bfloat16* __restrict__ dst, const void* __restrict__ src,
                          int rows_valid, int cols_valid, int src_ld, int dst_ld,
                          const int* __restrict__ fdt)
{
    int c = blockIdx.x * 256 + threadIdx.x;
    int r = blockIdx.y;
    if (c >= dst_ld) return;
    float v = 0.f;
    if (r < rows_valid && c < cols_valid) v = ldf(src, (long)r * src_ld + c, fdt[0]);
    dst[(long)r * dst_ld + c] = f2b(v);
}

// ---------------- vector-staged bf16 GEMM: C = A(M,K) * B(N,K)^T ----------------
// A,B padded (stride K, rows cover the full grid).
// EPI 0: store bf16 C[m*ldc+n].  EPI 1: relu(C/l[m] + bias[n]) -> bf16 vout.
template<int EPI>
__global__ __launch_bounds__(256)
void gemm_fast(const ushort* __restrict__ A, const ushort* __restrict__ B, int K,
               __hip_bfloat16* __restrict__ Cbf, int ldc,
               const float* __restrict__ lrow, const void* __restrict__ bias,
               __hip_bfloat16* __restrict__ vout, int Mvalid, int Nvalid,
               const int* __restrict__ fdt)
{
    __shared__ __align__(16) ushort sA[128 * 64];
    __shared__ __align__(16) ushort sB[128 * 64];
    const int tid = threadIdx.x;
    const int lane = tid & 63;
    const int wid = tid >> 6;
    const int wm = (wid >> 1) * 64;
    const int wn = (wid & 1) * 64;
    const long m0 = (long)blockIdx.y * 128;
    const long n0 = (long)blockIdx.x * 128;

    f32x4 acc[4][4];
#pragma unroll
    for (int i = 0; i < 4; ++i)
#pragma unroll
        for (int j = 0; j < 4; ++j) acc[i][j] = (f32x4){0.f, 0.f, 0.f, 0.f};

    const int lr = tid >> 3;          // 0..31
    const int lc = (tid & 7) * 8;     // element col offset
    const int koff = (lane >> 4) * 8;
    const int rowf = lane & 15;

    for (int k0 = 0; k0 < K; k0 += 64) {
        __syncthreads();
#pragma unroll
        for (int it = 0; it < 4; ++it) {
            int r = it * 32 + lr;
            *(uint4*)(&sA[r * 64 + lc]) = *(const uint4*)(A + (m0 + r) * (long)K + k0 + lc);
            *(uint4*)(&sB[r * 64 + lc]) = *(const uint4*)(B + (n0 + r) * (long)K + k0 + lc);
        }
        __syncthreads();
#pragma unroll
        for (int ks = 0; ks < 64; ks += 32) {
            short8 af[4], bfr[4];
            int kb = ks + koff;
#pragma unroll
            for (int f = 0; f < 4; ++f) {
                af[f]  = *(const short8*)(&sA[(wm + f * 16 + rowf) * 64 + kb]);
                bfr[f] = *(const short8*)(&sB[(wn + f * 16 + rowf) * 64 + kb]);
            }
#pragma unroll
            for (int i = 0; i < 4; ++i)
#pragma unroll
                for (int j = 0; j < 4; ++j)
                    acc[i][j] = __builtin_amdgcn_mfma_f32_16x16x32_bf16(af[i], bfr[j], acc[i][j], 0, 0, 0);
        }
    }

    const int f32 = (EPI == 1) ? fdt[0] : 0;
    const int rq = (lane >> 4) * 4;   // C/D: col = lane&15, row = (lane>>4)*4 + reg
#pragma unroll
    for (int i = 0; i < 4; ++i)
#pragma unroll
        for (int j = 0; j < 4; ++j)
#pragma unroll
            for (int rg = 0; rg < 4; ++rg) {
                long m = m0 + wm + i * 16 + rq + rg;
                long n = n0 + wn + j * 16 + (lane & 15);
                float v = acc[i][j][rg];
                if constexpr (EPI == 0) {
                    Cbf[m * ldc + n] = f2b(v);
                } else {
                    if (m < Mvalid && n < Nvalid) {
                        float den = fmaxf(lrow[m], 1e-30f);
                        float r = v / den + ldf(bias, n, f32);
                        vout[m * Nvalid + n] = f2b(sane(fmaxf(r, 0.f)));
                    }
                }
            }
}

// ---------------- GEMM1 fallback: raw operands, dtype-dual scalar staging ----------------
__global__ __launch_bounds__(256)
void gemm1_raw(const void* __restrict__ A, const void* __restrict__ B, int K,
               int lda, int ldb, int Ma, int Nb, int Kv,
               __hip_bfloat16* __restrict__ Cbf, int ldc, const int* __restrict__ fdt)
{
    __shared__ __align__(16) ushort sA[128 * 64];
    __shared__ __align__(16) ushort sB[128 * 64];
    const int f32 = fdt[0];
    const int tid = threadIdx.x;
    const int lane = tid & 63;
    const int wid = tid >> 6;
    const int wm = (wid >> 1) * 64;
    const int wn = (wid & 1) * 64;
    const long m0 = (long)blockIdx.y * 128;
    const long n0 = (long)blockIdx.x * 128;

    f32x4 acc[4][4];
#pragma unroll
    for (int i = 0; i < 4; ++i)
#pragma unroll
        for (int j = 0; j < 4; ++j) acc[i][j] = (f32x4){0.f, 0.f, 0.f, 0.f};

    const int lr = tid >> 3;
    const int lc = (tid & 7) * 8;
    const int koff = (lane >> 4) * 8;
    const int rowf = lane & 15;

    for (int k0 = 0; k0 < K; k0 += 64) {
        __syncthreads();
#pragma unroll
        for (int it = 0; it < 4; ++it) {
            int r = it * 32 + lr;
            long gm = m0 + r, gn = n0 + r;
            ushort va[8], vb[8];
#pragma unroll
            for (int e = 0; e < 8; ++e) {
                int k = k0 + lc + e;
                bool kok = (k < Kv);
                float fa = (kok && gm < Ma) ? ldf(A, gm * (long)lda + k, f32) : 0.f;
                float fb = (kok && gn < Nb) ? ldf(B, gn * (long)ldb + k, f32) : 0.f;
                va[e] = __hip_bfloat16_raw(f2b(fa)).x;
                vb[e] = __hip_bfloat16_raw(f2b(fb)).x;
            }
#pragma unroll
            for (int e = 0; e < 8; ++e) { sA[r * 64 + lc + e] = va[e]; sB[r * 64 + lc + e] = vb[e]; }
        }
        __syncthreads();
#pragma unroll
        for (int ks = 0; ks < 64; ks += 32) {
            short8 af[4], bfr[4];
            int kb = ks + koff;
#pragma unroll
            for (int f = 0; f < 4; ++f) {
                af[f]  = *(const short8*)(&sA[(wm + f * 16 + rowf) * 64 + kb]);
                bfr[f] = *(const short8*)(&sB[(wn + f * 16 + rowf) * 64 + kb]);
            }
#pragma unroll
            for (int i = 0; i < 4; ++i)
#pragma unroll
                for (int j = 0; j < 4; ++j)
                    acc[i][j] = __builtin_amdgcn_mfma_f32_16x16x32_bf16(af[i], bfr[j], acc[i][j], 0, 0, 0);
        }
    }

    const int rq = (lane >> 4) * 4;
#pragma unroll
    for (int i = 0; i < 4; ++i)
#pragma unroll
        for (int j = 0; j < 4; ++j)
#pragma unroll
            for (int rg = 0; rg < 4; ++rg) {
                long m = m0 + wm + i * 16 + rq + rg;
                long n = n0 + wn + j * 16 + (lane & 15);
                Cbf[m * ldc + n] = f2b(acc[i][j][rg]);
            }
}

// ---------------- asrc[j] = h[j,:]·a_src, adst[j] = h[j,:]·a_dst ----------------
__global__ void srcdst(const __hip_bfloat16* __restrict__ hT,
                       const void* __restrict__ a_src, const void* __restrict__ a_dst,
                       int Nv, int Nvp, float* __restrict__ asrc, float* __restrict__ adst,
                       const int* __restrict__ fdt)
{
    __shared__ float as[OUTF], ad[OUTF];
    const int f32 = fdt[0];
    int tid = threadIdx.x;
    for (int k = tid; k < OUTF; k += 256) { as[k] = ldf(a_src, k, f32); ad[k] = ldf(a_dst, k, f32); }
    __syncthreads();
    int j = blockIdx.x * 256 + tid;
    if (j >= Nv) return;
    float s1 = 0.f, s2 = 0.f;
    for (int o = 0; o < OUTF; ++o) {
        float hv = b2f(hT[(long)o * Nvp + j]);
        s1 += hv * as[o];
        s2 += hv * ad[o];
    }
    asrc[j] = s1;
    adst[j] = s2;
}

// ---------------- P = mask * exp(leaky(adst_i + asrc_j)), row sums l ----------------
__global__ void pbuild(const int* __restrict__ adj, const float* __restrict__ asrc,
                       const float* __restrict__ adst, int Nv, int Nvp, int ioff,
                       __hip_bfloat16* __restrict__ P, float* __restrict__ l)
{
    const int lane = threadIdx.x & 63, grp = threadIdx.x >> 6;
    const int j0 = blockIdx.x * 64, r0 = blockIdx.y * 64;
    const int j = j0 + lane;
    const float as = (j < Nv) ? asrc[j] : 0.f;
#pragma unroll
    for (int it = 0; it < 16; ++it) {
        int rr = it * 4 + grp;
        int r = r0 + rr;
        int i = (r < 901) ? r : r + ioff;
        float p = 0.f;
        if (r < NROWS && j < Nv) {
            bool m = (adj[(long)j * Nv + i] != 0) || (i == j);
            if (m) {
                float e = adst[i] + as;
                e = e > 0.f ? e : 0.2f * e;
                p = expf(fminf(e, 30.f));
            }
        }
        __hip_bfloat16 pb = f2b(p);
        if (r < 1792) P[(long)r * Nvp + j] = pb;
        float pv = b2f(pb);
        for (int o = 32; o; o >>= 1) pv += __shfl_down(pv, o);
        if (lane == 0 && r < NROWS) atomicAdd(&l[r], pv);
    }
}

// ---------------- CAM ----------------
__device__ __forceinline__ void block_reduce_atomic4(float a, float b, float c, float d, double* out)
{
    for (int o = 32; o; o >>= 1) {
        a += __shfl_down(a, o); b += __shfl_down(b, o);
        c += __shfl_down(c, o); d += __shfl_down(d, o);
    }
    __shared__ float s[4][4];
    int lane = threadIdx.x & 63, wv = threadIdx.x >> 6;
    if (lane == 0) { s[wv][0] = a; s[wv][1] = b; s[wv][2] = c; s[wv][3] = d; }
    __syncthreads();
    if (threadIdx.x < 4) {
        float v = s[0][threadIdx.x] + s[1][threadIdx.x] + s[2][threadIdx.x] + s[3][threadIdx.x];
        atomicAdd(out + threadIdx.x, (double)v);
    }
}

__device__ __forceinline__ void camY(int idx,
    const __hip_bfloat16* v0, const __hip_bfloat16* v1, const __hip_bfloat16* v2,
    const void* md, const void* lw1, const void* lb1, const void* gw1, const void* gb1,
    int f32, float& Yl, float& Yg)
{
    float x0 = b2f(v0[idx]), x1 = b2f(v1[idx]), x2 = b2f(v2[idx]), x3 = ldf(md, idx, f32);
    Yl = ldf(lw1,0,f32)*x0 + ldf(lw1,1,f32)*x1 + ldf(lw1,2,f32)*x2 + ldf(lw1,3,f32)*x3 + ldf(lb1,0,f32);
    Yg = ldf(gw1,0,f32)*x0 + ldf(gw1,1,f32)*x1 + ldf(gw1,2,f32)*x2 + ldf(gw1,3,f32)*x3 + ldf(gb1,0,f32);
}

__global__ void cam_pass1(const __hip_bfloat16* __restrict__ v0, const __hip_bfloat16* __restrict__ v1,
                          const __hip_bfloat16* __restrict__ v2, const void* __restrict__ md,
                          const void* __restrict__ lw1, const void* __restrict__ lb1,
                          const void* __restrict__ gw1, const void* __restrict__ gb1,
                          double* __restrict__ sD, const int* __restrict__ fdt)
{
    int idx = blockIdx.x * 256 + threadIdx.x;
    float a = 0, b = 0, c = 0, d = 0;
    if (idx < NEL) {
        float Yl, Yg;
        camY(idx, v0, v1, v2, md, lw1, lb1, gw1, gb1, fdt[0], Yl, Yg);
        a = Yl; b = Yl * Yl; c = Yg; d = Yg * Yg;
    }
    block_reduce_atomic4(a, b, c, d, sD);
}

__global__ void cam_fin1(const double* __restrict__ sD, float* __restrict__ sF)
{
    if (threadIdx.x == 0) {
        double n = (double)NEL;
        double ml = sD[0] / n, vl = sD[1] / n - ml * ml;
        double mg = sD[2] / n, vg = sD[3] / n - mg * mg;
        if (vl < 0.0) vl = 0.0;
        if (vg < 0.0) vg = 0.0;
        sF[0] = (float)ml; sF[1] = (float)(1.0 / sqrt(vl + 1e-5));
        sF[2] = (float)mg; sF[3] = (float)(1.0 / sqrt(vg + 1e-5));
    }
}

__global__ void cam_pass2(const __hip_bfloat16* __restrict__ v0, const __hip_bfloat16* __restrict__ v1,
                          const __hip_bfloat16* __restrict__ v2, const void* __restrict__ md,
                          const void* __restrict__ lw1, const void* __restrict__ lb1,
                          const void* __restrict__ gw1, const void* __restrict__ gb1,
                          const float* __restrict__ sF, double* __restrict__ sD,
                          const int* __restrict__ fdt)
{
    int idx = blockIdx.x * 256 + threadIdx.x;
    float a = 0, b = 0, c = 0, d = 0;
    if (idx < NEL) {
        float Yl, Yg;
        camY(idx, v0, v1, v2, md, lw1, lb1, gw1, gb1, fdt[0], Yl, Yg);
        float zl = fmaxf((Yl - sF[0]) * sF[1], 0.f);
        float zg = fmaxf((Yg - sF[2]) * sF[3], 0.f);
        a = zl; b = zl * zl; c = zg; d = zg * zg;
    }
    block_reduce_atomic4(a, b, c, d, sD + 4);
}

__global__ void cam_fin2(const double* __restrict__ sD, float* __restrict__ sF,
                         const void* __restrict__ lw2, const void* __restrict__ gw2,
                         const int* __restrict__ fdt)
{
    if (threadIdx.x == 0) {
        const int f32 = fdt[0];
        double n = (double)NEL;
        double mzl = sD[4] / n, vzl = sD[5] / n - mzl * mzl;
        double mzg = sD[6] / n, vzg = sD[7] / n - mzg * mzg;
        if (vzl < 0.0) vzl = 0.0;
        if (vzg < 0.0) vzg = 0.0;
        sF[4] = (float)mzl; sF[5] = (float)mzg;
        for (int c = 0; c < 4; ++c) {
            double wl = (double)ldf(lw2, c, f32);
            double wg = (double)ldf(gw2, c, f32);
            sF[6 + c]  = (float)(wl / sqrt(wl * wl * vzl + 1e-5));
            sF[10 + c] = (float)(wg / sqrt(wg * wg * vzg + 1e-5));
        }
    }
}

__global__ void cam_fuse(const __hip_bfloat16* __restrict__ v0, const __hip_bfloat16* __restrict__ v1,
                         const __hip_bfloat16* __restrict__ v2, const void* __restrict__ md,
                         const void* __restrict__ lw1, const void* __restrict__ lb1,
                         const void* __restrict__ gw1, const void* __restrict__ gb1,
                         const float* __restrict__ sF, float* __restrict__ sumx,
                         const int* __restrict__ fdt)
{
    int idx = blockIdx.x * 256 + threadIdx.x;
    if (idx >= NEL) return;
    const int f32 = fdt[0];
    float Yl, Yg;
    camY(idx, v0, v1, v2, md, lw1, lb1, gw1, gb1, f32, Yl, Yg);
    float zl = fmaxf((Yl - sF[0]) * sF[1], 0.f);
    float zg = fmaxf((Yg - sF[2]) * sF[3], 0.f);
    float dzl = zl - sF[4], dzg = zg - sF[5];
    float x[4] = {b2f(v0[idx]), b2f(v1[idx]), b2f(v2[idx]), ldf(md, idx, f32)};
    float s = 0.f;
#pragma unroll
    for (int c = 0; c < 4; ++c) {
        float t = sF[6 + c] * dzl + sF[10 + c] * dzg;
        s += x[c] / (1.f + expf(-t));
    }
    sumx[idx] = 0.25f * s;
}

// ---------------- collapsed MLP head ----------------
__global__ void mlp_head(const void* __restrict__ mW2, const void* __restrict__ mW3,
                         const void* __restrict__ mW4, const void* __restrict__ mb1,
                         const void* __restrict__ mb2, const void* __restrict__ mb3,
                         const void* __restrict__ mb4, float* __restrict__ u1out,
                         float* __restrict__ sF, const int* __restrict__ fdt)
{
    __shared__ float u3[64];
    __shared__ float u2[512];
    __shared__ float u1[1024];
    __shared__ float red[4];
    const int f32 = fdt[0];
    int t = threadIdx.x;
    if (t < 64) u3[t] = ldf(mW4, t, f32);
    __syncthreads();
    for (int k = t; k < 512; k += 256) {
        float s = 0.f;
        for (int o = 0; o < 64; ++o) s += ldf(mW3, o * 512 + k, f32) * u3[o];
        u2[k] = s;
    }
    __syncthreads();
    for (int k = t; k < 1024; k += 256) {
        float s = 0.f;
        for (int o = 0; o < 512; ++o) s += ldf(mW2, o * 1024 + k, f32) * u2[o];
        u1[k] = s;
    }
    __syncthreads();
    float p = 0.f;
    for (int k = t; k < 1024; k += 256) { p += ldf(mb1, k, f32) * u1[k]; u1out[k] = u1[k]; }
    for (int k = t; k < 512; k += 256) p += ldf(mb2, k, f32) * u2[k];
    if (t < 64) p += ldf(mb3, t, f32) * u3[t];
    for (int o = 32; o; o >>= 1) p += __shfl_down(p, o);
    int lane = t & 63, wv = t >> 6;
    if (!lane) red[wv] = p;
    __syncthreads();
    if (t == 0) sF[14] = red[0] + red[1] + red[2] + red[3] + ldf(mb4, 0, f32);
}

__global__ void mlp_u0(const void* __restrict__ mW1, const float* __restrict__ u1,
                       float* __restrict__ u0, const int* __restrict__ fdt)
{
    int k = blockIdx.x * 256 + threadIdx.x;
    if (k >= 1802) return;
    const int f32 = fdt[0];
    float s = 0.f;
    for (int o = 0; o < 1024; ++o) s += ldf(mW1, (long)o * 1802 + k, f32) * u1[o];
    u0[k] = s;
}

__global__ void rowdot(const float* __restrict__ sumx, const float* __restrict__ u0,
                       float* __restrict__ f, float* __restrict__ g)
{
    int r = blockIdx.x, t = threadIdx.x;
    float fa = 0.f, ga = 0.f;
    for (int o = t; o < OUTF; o += 256) {
        float v = sumx[(long)r * OUTF + o];
        fa += v * u0[o];
        ga += v * u0[OUTF + o];
    }
    for (int o = 32; o; o >>= 1) { fa += __shfl_down(fa, o); ga += __shfl_down(ga, o); }
    __shared__ float s[4][2];
    int lane = t & 63, wv = t >> 6;
    if (!lane) { s[wv][0] = fa; s[wv][1] = ga; }
    __syncthreads();
    if (t == 0) {
        f[r] = s[0][0] + s[1][0] + s[2][0] + s[3][0];
        g[r] = s[0][1] + s[1][1] + s[2][1] + s[3][1];
    }
}

__global__ void score(const int* __restrict__ ts, const float* __restrict__ f,
                      const float* __restrict__ g, const float* __restrict__ sF,
                      void* __restrict__ out, const int* __restrict__ fdt)
{
    int p = blockIdx.x * 256 + threadIdx.x;
    if (p >= 4096) return;
    float v = sane(f[ts[2 * p]] + g[ts[2 * p + 1]] + sF[14]);
    if (fdt[0]) ((float*)out)[p] = v;
    else        ((__hip_bfloat16*)out)[p] = f2b(v);
}

// ---------------- launch ----------------
extern "C" void kernel_launch(void* const* d_in, const int* in_sizes, int n_in,
                              void* d_out, int out_size, void* d_ws, size_t ws_size,
                              hipStream_t stream)
{
    const int NVv[3]   = {2060, 2459, 3929};
    const int NVPv[3]  = {2176, 2560, 3968};
    const int IOFFv[3] = {282, 681, 2151};
    const int ADJ_I[3] = {0, 1, 2}, FEAT_I[3] = {4, 5, 6}, W_I[3] = {8, 12, 16},
              AS_I[3] = {9, 13, 17}, AD_I[3] = {10, 14, 18}, BV_I[3] = {11, 15, 19};

    char* w = (char*)d_ws;
    size_t off = 0;
    auto alloc = [&](size_t b) { void* p = w + off; off += (b + 255) & ~(size_t)255; return p; };

    ushort* hT   = (ushort*)alloc(1024ULL * 3968 * 2);            // 8.1 MB
    ushort* Pexp = (ushort*)alloc(1792ULL * 3968 * 2);            // 14.2 MB
    __hip_bfloat16* voutb[3];
    for (int v = 0; v < 3; ++v)
        voutb[v] = (__hip_bfloat16*)alloc((size_t)NROWS * OUTF * 2);  // 3x 3.2 MB
    float*  asrc   = (float*)alloc(3968 * 4);
    float*  adst   = (float*)alloc(3968 * 4);
    float*  lrow   = (float*)alloc(1792 * 4);
    double* statsD = (double*)alloc(8 * 8);
    float*  statsF = (float*)alloc(16 * 4);
    float*  u1     = (float*)alloc(1024 * 4);
    float*  u0     = (float*)alloc(1802 * 4);
    float*  fv     = (float*)alloc(NROWS * 4);
    float*  gv     = (float*)alloc(NROWS * 4);
    int*    fdt    = (int*)alloc(4);
    // fast-path-only: featPad allocated last so the compact set fits small ws
    ushort* featPad = (ushort*)alloc(3968ULL * 3968 * 2);         // 31.5 MB
    const bool use_fast = (ws_size >= off);
    // overlays on dead regions
    ushort* Wpad = Pexp;            // Wpad (8.1 MB) lives in Pexp (14.2 MB) during gemm1
    float*  sumx = (float*)hT;      // hT dead after view loop; sumx 6.4 MB < 8.1 MB

    probe_dtype<<<1, 256, 0, stream>>>((const ushort*)d_in[9], fdt);

    for (int v = 0; v < 3; ++v) {
        int Nv = NVv[v], Nvp = NVPv[v], ioff2 = IOFFv[v];
        int Kp = (Nv + 63) & ~63;

        dim3 gg1(Nvp / 128, 8);   // hT[1024, Nvp] = W · feat^T
        if (use_fast) {
            dim3 gpk((Nvp + 255) / 256, Nvp);
            pack_dual<<<gpk, 256, 0, stream>>>((__hip_bfloat16*)featPad, d_in[FEAT_I[v]],
                                               Nv, Nv, Nv, Nvp, fdt);
            dim3 gpw((Nvp + 255) / 256, 1024);
            pack_dual<<<gpw, 256, 0, stream>>>((__hip_bfloat16*)Wpad, d_in[W_I[v]],
                                               901, Nv, Nv, Nvp, fdt);
            gemm_fast<0><<<gg1, 256, 0, stream>>>(Wpad, featPad, Nvp,
                (__hip_bfloat16*)hT, Nvp, nullptr, nullptr, nullptr, 0, 0, fdt);
        } else {
            gemm1_raw<<<gg1, 256, 0, stream>>>(d_in[W_I[v]], d_in[FEAT_I[v]], Kp,
                                               Nv, Nv, 901, Nv, Nv,
                                               (__hip_bfloat16*)hT, Nvp, fdt);
        }

        srcdst<<<(Nv + 255) / 256, 256, 0, stream>>>((const __hip_bfloat16*)hT,
            d_in[AS_I[v]], d_in[AD_I[v]], Nv, Nvp, asrc, adst, fdt);

        zerof<<<7, 256, 0, stream>>>(lrow, 1792);
        dim3 gp(Nvp / 64, 28);
        pbuild<<<gp, 256, 0, stream>>>((const int*)d_in[ADJ_I[v]], asrc, adst, Nv, Nvp, ioff2,
                                       (__hip_bfloat16*)Pexp, lrow);

        dim3 gg2(8, 14);          // vout[1778,901] = relu(P·h / l + b)
        gemm_fast<1><<<gg2, 256, 0, stream>>>(Pexp, hT, Nvp,
            nullptr, 0, lrow, d_in[BV_I[v]], voutb[v], NROWS, OUTF, fdt);
    }

    zerof<<<1, 256, 0, stream>>>((float*)statsD, 16);
    int gb = (NEL + 255) / 256;
    cam_pass1<<<gb, 256, 0, stream>>>(voutb[0], voutb[1], voutb[2], d_in[7],
        d_in[20], d_in[21], d_in[24], d_in[25], statsD, fdt);
    cam_fin1<<<1, 64, 0, stream>>>(statsD, statsF);
    cam_pass2<<<gb, 256, 0, stream>>>(voutb[0], voutb[1], voutb[2], d_in[7],
        d_in[20], d_in[21], d_in[24], d_in[25], statsF, statsD, fdt);
    cam_fin2<<<1, 64, 0, stream>>>(statsD, statsF, d_in[22], d_in[26], fdt);
    cam_fuse<<<gb, 256, 0, stream>>>(voutb[0], voutb[1], voutb[2], d_in[7],
        d_in[20], d_in[21], d_in[24], d_in[25], statsF, sumx, fdt);

    mlp_head<<<1, 256, 0, stream>>>(d_in[30], d_in[32], d_in[34], d_in[29],
        d_in[31], d_in[33], d_in[35], u1, statsF, fdt);
    mlp_u0<<<8, 256, 0, stream>>>(d_in[28], u1, u0, fdt);
    rowdot<<<NROWS, 256, 0, stream>>>(sumx, u0, fv, gv);
    score<<<16, 256, 0, stream>>>((const int*)d_in[3], fv, gv, statsF, d_out, fdt);
}

// Round 6
// 1446.451 us; speedup vs baseline: 2.3416x; 1.2915x over previous
//
#include <hip/hip_runtime.h>
#include <hip/hip_bf16.h>
#include <stdint.h>

typedef __attribute__((ext_vector_type(8))) short short8;
typedef __attribute__((ext_vector_type(4))) float f32x4;

#define AS1 __attribute__((address_space(1)))
#define AS3 __attribute__((address_space(3)))

#define NEL 1601978   // 1778*901
#define NROWS 1778
#define OUTF 901

__device__ __forceinline__ float b2f(__hip_bfloat16 x) { return __bfloat162float(x); }
__device__ __forceinline__ __hip_bfloat16 f2b(float x) { return __float2bfloat16(x); }
__device__ __forceinline__ float sane(float v) { return isfinite(v) ? v : 0.f; }

// dtype-dual load: flag==1 -> fp32 array, flag==0 -> bf16 array
__device__ __forceinline__ float ldf(const void* p, long i, int f32)
{
    return f32 ? ((const float*)p)[i] : b2f(((const __hip_bfloat16*)p)[i]);
}

// ---------------- dtype probe ----------------
__global__ void probe_dtype(const ushort* __restrict__ p, int* __restrict__ fdt)
{
    int t = threadIdx.x;
    int cnt = 0;
    for (int i = t; i < 512; i += 256) {
        int ex = (p[i] >> 7) & 0xFF;
        if (ex >= 0x85) cnt++;
    }
    for (int o = 32; o; o >>= 1) cnt += __shfl_down(cnt, o);
    __shared__ int s[4];
    if ((t & 63) == 0) s[t >> 6] = cnt;
    __syncthreads();
    if (t == 0) fdt[0] = (s[0] + s[1] + s[2] + s[3] > 16) ? 1 : 0;
}

// ---------------- zero scratch ----------------
__global__ void zerof(float* __restrict__ p, int n)
{
    int i = blockIdx.x * 256 + threadIdx.x;
    if (i < n) p[i] = 0.f;
}

// ---------------- pack (fp32|bf16) -> padded bf16 ----------------
__global__ void pack_dual(__hip_bfloat16* __restrict__ dst, const void* __restrict__ src,
                          int rows_valid, int cols_valid, int src_ld, int dst_ld,
                          const int* __restrict__ fdt)
{
    int c = blockIdx.x * 256 + threadIdx.x;
    int r = blockIdx.y;
    if (c >= dst_ld) return;
    float v = 0.f;
    if (r < rows_valid && c < cols_valid) v = ldf(src, (long)r * src_ld + c, fdt[0]);
    dst[(long)r * dst_ld + c] = f2b(v);
}

// ---------------- vector-staged bf16 GEMM: C = A(M,K) * B(N,K)^T ----------------
// A,B padded (stride K, rows cover the full grid), K*2 bytes 16B-aligned.
// Staging: global_load_lds width 16 (async direct-to-LDS, m97 pattern).
// EPI 0: store bf16 C[m*ldc+n].  EPI 1: relu(C/l[m] + bias[n]) -> bf16 vout.
template<int EPI>
__global__ __launch_bounds__(256)
void gemm_fast(const ushort* __restrict__ A, const ushort* __restrict__ B, int K,
               __hip_bfloat16* __restrict__ Cbf, int ldc,
               const float* __restrict__ lrow, const void* __restrict__ bias,
               __hip_bfloat16* __restrict__ vout, int Mvalid, int Nvalid,
               const int* __restrict__ fdt)
{
    __shared__ __align__(16) ushort sA[128 * 64];
    __shared__ __align__(16) ushort sB[128 * 64];
    const int tid = threadIdx.x;
    const int lane = tid & 63;
    const int wid = tid >> 6;
    const int wm = (wid >> 1) * 64;
    const int wn = (wid & 1) * 64;
    const long m0 = (long)blockIdx.y * 128;
    const long n0 = (long)blockIdx.x * 128;

    f32x4 acc[4][4];
#pragma unroll
    for (int i = 0; i < 4; ++i)
#pragma unroll
        for (int j = 0; j < 4; ++j) acc[i][j] = (f32x4){0.f, 0.f, 0.f, 0.f};

    const int rsub = lane >> 3;       // 0..7 row within 8-row slab
    const int csub = (lane & 7) * 8;  // element col offset; lane LDS off = lane*16B
    const int koff = (lane >> 4) * 8;
    const int rowf = lane & 15;

    for (int k0 = 0; k0 < K; k0 += 64) {
        __syncthreads();
#pragma unroll
        for (int it = 0; it < 4; ++it) {
            int rb = wid * 32 + it * 8;
            int r = rb + rsub;
            __builtin_amdgcn_global_load_lds(
                (const AS1 uint*)(const void*)(A + (m0 + r) * (long)K + k0 + csub),
                (AS3 uint*)&sA[r * 64 + csub], 16, 0, 0);
            __builtin_amdgcn_global_load_lds(
                (const AS1 uint*)(const void*)(B + (n0 + r) * (long)K + k0 + csub),
                (AS3 uint*)&sB[r * 64 + csub], 16, 0, 0);
        }
        __syncthreads();   // drains vmcnt(0): LDS-direct loads complete
#pragma unroll
        for (int ks = 0; ks < 64; ks += 32) {
            short8 af[4], bfr[4];
            int kb = ks + koff;
#pragma unroll
            for (int f = 0; f < 4; ++f) {
                af[f]  = *(const short8*)(&sA[(wm + f * 16 + rowf) * 64 + kb]);
                bfr[f] = *(const short8*)(&sB[(wn + f * 16 + rowf) * 64 + kb]);
            }
#pragma unroll
            for (int i = 0; i < 4; ++i)
#pragma unroll
                for (int j = 0; j < 4; ++j)
                    acc[i][j] = __builtin_amdgcn_mfma_f32_16x16x32_bf16(af[i], bfr[j], acc[i][j], 0, 0, 0);
        }
    }

    const int f32 = (EPI == 1) ? fdt[0] : 0;
    const int rq = (lane >> 4) * 4;   // C/D: col = lane&15, row = (lane>>4)*4 + reg
#pragma unroll
    for (int i = 0; i < 4; ++i)
#pragma unroll
        for (int j = 0; j < 4; ++j)
#pragma unroll
            for (int rg = 0; rg < 4; ++rg) {
                long m = m0 + wm + i * 16 + rq + rg;
                long n = n0 + wn + j * 16 + (lane & 15);
                float v = acc[i][j][rg];
                if constexpr (EPI == 0) {
                    Cbf[m * ldc + n] = f2b(v);
                } else {
                    if (m < Mvalid && n < Nvalid) {
                        float den = fmaxf(lrow[m], 1e-30f);
                        float r = v / den + ldf(bias, n, f32);
                        vout[m * Nvalid + n] = f2b(sane(fmaxf(r, 0.f)));
                    }
                }
            }
}

// ---------------- GEMM1 fallback: raw operands, dtype-dual scalar staging ----------------
__global__ __launch_bounds__(256)
void gemm1_raw(const void* __restrict__ A, const void* __restrict__ B, int K,
               int lda, int ldb, int Ma, int Nb, int Kv,
               __hip_bfloat16* __restrict__ Cbf, int ldc, const int* __restrict__ fdt)
{
    __shared__ __align__(16) ushort sA[128 * 64];
    __shared__ __align__(16) ushort sB[128 * 64];
    const int f32 = fdt[0];
    const int tid = threadIdx.x;
    const int lane = tid & 63;
    const int wid = tid >> 6;
    const int wm = (wid >> 1) * 64;
    const int wn = (wid & 1) * 64;
    const long m0 = (long)blockIdx.y * 128;
    const long n0 = (long)blockIdx.x * 128;

    f32x4 acc[4][4];
#pragma unroll
    for (int i = 0; i < 4; ++i)
#pragma unroll
        for (int j = 0; j < 4; ++j) acc[i][j] = (f32x4){0.f, 0.f, 0.f, 0.f};

    const int lr = tid >> 3;
    const int lc = (tid & 7) * 8;
    const int koff = (lane >> 4) * 8;
    const int rowf = lane & 15;

    for (int k0 = 0; k0 < K; k0 += 64) {
        __syncthreads();
#pragma unroll
        for (int it = 0; it < 4; ++it) {
            int r = it * 32 + lr;
            long gm = m0 + r, gn = n0 + r;
            ushort va[8], vb[8];
#pragma unroll
            for (int e = 0; e < 8; ++e) {
                int k = k0 + lc + e;
                bool kok = (k < Kv);
                float fa = (kok && gm < Ma) ? ldf(A, gm * (long)lda + k, f32) : 0.f;
                float fb = (kok && gn < Nb) ? ldf(B, gn * (long)ldb + k, f32) : 0.f;
                va[e] = __hip_bfloat16_raw(f2b(fa)).x;
                vb[e] = __hip_bfloat16_raw(f2b(fb)).x;
            }
#pragma unroll
            for (int e = 0; e < 8; ++e) { sA[r * 64 + lc + e] = va[e]; sB[r * 64 + lc + e] = vb[e]; }
        }
        __syncthreads();
#pragma unroll
        for (int ks = 0; ks < 64; ks += 32) {
            short8 af[4], bfr[4];
            int kb = ks + koff;
#pragma unroll
            for (int f = 0; f < 4; ++f) {
                af[f]  = *(const short8*)(&sA[(wm + f * 16 + rowf) * 64 + kb]);
                bfr[f] = *(const short8*)(&sB[(wn + f * 16 + rowf) * 64 + kb]);
            }
#pragma unroll
            for (int i = 0; i < 4; ++i)
#pragma unroll
                for (int j = 0; j < 4; ++j)
                    acc[i][j] = __builtin_amdgcn_mfma_f32_16x16x32_bf16(af[i], bfr[j], acc[i][j], 0, 0, 0);
        }
    }

    const int rq = (lane >> 4) * 4;
#pragma unroll
    for (int i = 0; i < 4; ++i)
#pragma unroll
        for (int j = 0; j < 4; ++j)
#pragma unroll
            for (int rg = 0; rg < 4; ++rg) {
                long m = m0 + wm + i * 16 + rq + rg;
                long n = n0 + wn + j * 16 + (lane & 15);
                Cbf[m * ldc + n] = f2b(acc[i][j][rg]);
            }
}

// ---------------- asrc[j] = h[j,:]·a_src, adst[j] = h[j,:]·a_dst ----------------
__global__ void srcdst(const __hip_bfloat16* __restrict__ hT,
                       const void* __restrict__ a_src, const void* __restrict__ a_dst,
                       int Nv, int Nvp, float* __restrict__ asrc, float* __restrict__ adst,
                       const int* __restrict__ fdt)
{
    __shared__ float as[OUTF], ad[OUTF];
    const int f32 = fdt[0];
    int tid = threadIdx.x;
    for (int k = tid; k < OUTF; k += 256) { as[k] = ldf(a_src, k, f32); ad[k] = ldf(a_dst, k, f32); }
    __syncthreads();
    int j = blockIdx.x * 256 + tid;
    if (j >= Nv) return;
    float s1 = 0.f, s2 = 0.f;
    for (int o = 0; o < OUTF; ++o) {
        float hv = b2f(hT[(long)o * Nvp + j]);
        s1 += hv * as[o];
        s2 += hv * ad[o];
    }
    asrc[j] = s1;
    adst[j] = s2;
}

// ---------------- P = mask * exp(leaky(adst_i + asrc_j)), row sums l ----------------
__global__ void pbuild(const int* __restrict__ adj, const float* __restrict__ asrc,
                       const float* __restrict__ adst, int Nv, int Nvp, int ioff,
                       __hip_bfloat16* __restrict__ P, float* __restrict__ l)
{
    const int lane = threadIdx.x & 63, grp = threadIdx.x >> 6;
    const int j0 = blockIdx.x * 64, r0 = blockIdx.y * 64;
    const int j = j0 + lane;
    const float as = (j < Nv) ? asrc[j] : 0.f;
#pragma unroll
    for (int it = 0; it < 16; ++it) {
        int rr = it * 4 + grp;
        int r = r0 + rr;
        int i = (r < 901) ? r : r + ioff;
        float p = 0.f;
        if (r < NROWS && j < Nv) {
            bool m = (adj[(long)j * Nv + i] != 0) || (i == j);
            if (m) {
                float e = adst[i] + as;
                e = e > 0.f ? e : 0.2f * e;
                p = expf(fminf(e, 30.f));
            }
        }
        __hip_bfloat16 pb = f2b(p);
        if (r < 1792) P[(long)r * Nvp + j] = pb;
        float pv = b2f(pb);
        for (int o = 32; o; o >>= 1) pv += __shfl_down(pv, o);
        if (lane == 0 && r < NROWS) atomicAdd(&l[r], pv);
    }
}

// ---------------- CAM ----------------
__device__ __forceinline__ void block_reduce_atomic4(float a, float b, float c, float d, double* out)
{
    for (int o = 32; o; o >>= 1) {
        a += __shfl_down(a, o); b += __shfl_down(b, o);
        c += __shfl_down(c, o); d += __shfl_down(d, o);
    }
    __shared__ float s[4][4];
    int lane = threadIdx.x & 63, wv = threadIdx.x >> 6;
    if (lane == 0) { s[wv][0] = a; s[wv][1] = b; s[wv][2] = c; s[wv][3] = d; }
    __syncthreads();
    if (threadIdx.x < 4) {
        float v = s[0][threadIdx.x] + s[1][threadIdx.x] + s[2][threadIdx.x] + s[3][threadIdx.x];
        atomicAdd(out + threadIdx.x, (double)v);
    }
}

__device__ __forceinline__ void camY(int idx,
    const __hip_bfloat16* v0, const __hip_bfloat16* v1, const __hip_bfloat16* v2,
    const void* md, const void* lw1, const void* lb1, const void* gw1, const void* gb1,
    int f32, float& Yl, float& Yg)
{
    float x0 = b2f(v0[idx]), x1 = b2f(v1[idx]), x2 = b2f(v2[idx]), x3 = ldf(md, idx, f32);
    Yl = ldf(lw1,0,f32)*x0 + ldf(lw1,1,f32)*x1 + ldf(lw1,2,f32)*x2 + ldf(lw1,3,f32)*x3 + ldf(lb1,0,f32);
    Yg = ldf(gw1,0,f32)*x0 + ldf(gw1,1,f32)*x1 + ldf(gw1,2,f32)*x2 + ldf(gw1,3,f32)*x3 + ldf(gb1,0,f32);
}

__global__ void cam_pass1(const __hip_bfloat16* __restrict__ v0, const __hip_bfloat16* __restrict__ v1,
                          const __hip_bfloat16* __restrict__ v2, const void* __restrict__ md,
                          const void* __restrict__ lw1, const void* __restrict__ lb1,
                          const void* __restrict__ gw1, const void* __restrict__ gb1,
                          double* __restrict__ sD, const int* __restrict__ fdt)
{
    int idx = blockIdx.x * 256 + threadIdx.x;
    float a = 0, b = 0, c = 0, d = 0;
    if (idx < NEL) {
        float Yl, Yg;
        camY(idx, v0, v1, v2, md, lw1, lb1, gw1, gb1, fdt[0], Yl, Yg);
        a = Yl; b = Yl * Yl; c = Yg; d = Yg * Yg;
    }
    block_reduce_atomic4(a, b, c, d, sD);
}

__global__ void cam_fin1(const double* __restrict__ sD, float* __restrict__ sF)
{
    if (threadIdx.x == 0) {
        double n = (double)NEL;
        double ml = sD[0] / n, vl = sD[1] / n - ml * ml;
        double mg = sD[2] / n, vg = sD[3] / n - mg * mg;
        if (vl < 0.0) vl = 0.0;
        if (vg < 0.0) vg = 0.0;
        sF[0] = (float)ml; sF[1] = (float)(1.0 / sqrt(vl + 1e-5));
        sF[2] = (float)mg; sF[3] = (float)(1.0 / sqrt(vg + 1e-5));
    }
}

__global__ void cam_pass2(const __hip_bfloat16* __restrict__ v0, const __hip_bfloat16* __restrict__ v1,
                          const __hip_bfloat16* __restrict__ v2, const void* __restrict__ md,
                          const void* __restrict__ lw1, const void* __restrict__ lb1,
                          const void* __restrict__ gw1, const void* __restrict__ gb1,
                          const float* __restrict__ sF, double* __restrict__ sD,
                          const int* __restrict__ fdt)
{
    int idx = blockIdx.x * 256 + threadIdx.x;
    float a = 0, b = 0, c = 0, d = 0;
    if (idx < NEL) {
        float Yl, Yg;
        camY(idx, v0, v1, v2, md, lw1, lb1, gw1, gb1, fdt[0], Yl, Yg);
        float zl = fmaxf((Yl - sF[0]) * sF[1], 0.f);
        float zg = fmaxf((Yg - sF[2]) * sF[3], 0.f);
        a = zl; b = zl * zl; c = zg; d = zg * zg;
    }
    block_reduce_atomic4(a, b, c, d, sD + 4);
}

__global__ void cam_fin2(const double* __restrict__ sD, float* __restrict__ sF,
                         const void* __restrict__ lw2, const void* __restrict__ gw2,
                         const int* __restrict__ fdt)
{
    if (threadIdx.x == 0) {
        const int f32 = fdt[0];
        double n = (double)NEL;
        double mzl = sD[4] / n, vzl = sD[5] / n - mzl * mzl;
        double mzg = sD[6] / n, vzg = sD[7] / n - mzg * mzg;
        if (vzl < 0.0) vzl = 0.0;
        if (vzg < 0.0) vzg = 0.0;
        sF[4] = (float)mzl; sF[5] = (float)mzg;
        for (int c = 0; c < 4; ++c) {
            double wl = (double)ldf(lw2, c, f32);
            double wg = (double)ldf(gw2, c, f32);
            sF[6 + c]  = (float)(wl / sqrt(wl * wl * vzl + 1e-5));
            sF[10 + c] = (float)(wg / sqrt(wg * wg * vzg + 1e-5));
        }
    }
}

__global__ void cam_fuse(const __hip_bfloat16* __restrict__ v0, const __hip_bfloat16* __restrict__ v1,
                         const __hip_bfloat16* __restrict__ v2, const void* __restrict__ md,
                         const void* __restrict__ lw1, const void* __restrict__ lb1,
                         const void* __restrict__ gw1, const void* __restrict__ gb1,
                         const float* __restrict__ sF, float* __restrict__ sumx,
                         const int* __restrict__ fdt)
{
    int idx = blockIdx.x * 256 + threadIdx.x;
    if (idx >= NEL) return;
    const int f32 = fdt[0];
    float Yl, Yg;
    camY(idx, v0, v1, v2, md, lw1, lb1, gw1, gb1, f32, Yl, Yg);
    float zl = fmaxf((Yl - sF[0]) * sF[1], 0.f);
    float zg = fmaxf((Yg - sF[2]) * sF[3], 0.f);
    float dzl = zl - sF[4], dzg = zg - sF[5];
    float x[4] = {b2f(v0[idx]), b2f(v1[idx]), b2f(v2[idx]), ldf(md, idx, f32)};
    float s = 0.f;
#pragma unroll
    for (int c = 0; c < 4; ++c) {
        float t = sF[6 + c] * dzl + sF[10 + c] * dzg;
        s += x[c] / (1.f + expf(-t));
    }
    sumx[idx] = 0.25f * s;
}

// ---------------- collapsed MLP head (parallel, multi-kernel) ----------------
// u3=mW4; u2=mW3^T u3; u1=mW2^T u2; u0=mW1^T u1; bc=mb1·u1+mb2·u2+mb3·u3+mb4
__global__ void mlp_a(const void* __restrict__ mW3, const void* __restrict__ mW4,
                      const void* __restrict__ mb2, const void* __restrict__ mb3,
                      const void* __restrict__ mb4,
                      float* __restrict__ u3g, float* __restrict__ u2g,
                      float* __restrict__ sF, const int* __restrict__ fdt)
{
    __shared__ float u3[64];
    __shared__ float red[4];
    const int f32 = fdt[0];
    int t = threadIdx.x;
    if (t < 64) { float v = ldf(mW4, t, f32); u3[t] = v; u3g[t] = v; }
    __syncthreads();
    float part = 0.f;
    for (int k = t; k < 512; k += 256) {
        float s = 0.f;
#pragma unroll
        for (int o = 0; o < 64; ++o) s += ldf(mW3, o * 512 + k, f32) * u3[o];
        u2g[k] = s;
        part += ldf(mb2, k, f32) * s;
    }
    if (t < 64) part += ldf(mb3, t, f32) * u3[t];
    for (int o = 32; o; o >>= 1) part += __shfl_down(part, o);
    if ((t & 63) == 0) red[t >> 6] = part;
    __syncthreads();
    if (t == 0) sF[15] = red[0] + red[1] + red[2] + red[3] + ldf(mb4, 0, f32);
}

// stage1: part1[ob][k] = sum over o-chunk ob of mW2[o][k]*u2[o]; grid (4, 8)
__global__ void mlp_b1(const void* __restrict__ mW2, const float* __restrict__ u2g,
                       float* __restrict__ part1, const int* __restrict__ fdt)
{
    int k = blockIdx.x * 256 + threadIdx.x;
    int o0 = blockIdx.y * 64;
    const int f32 = fdt[0];
    float s = 0.f;
#pragma unroll
    for (int oi = 0; oi < 64; ++oi) s += ldf(mW2, (long)(o0 + oi) * 1024 + k, f32) * u2g[o0 + oi];
    part1[blockIdx.y * 1024 + k] = s;
}

// stage2: u1[k] = sum part1; grid 4
__global__ void mlp_b2(const float* __restrict__ part1, float* __restrict__ u1g)
{
    int k = blockIdx.x * 256 + threadIdx.x;
    float s = 0.f;
#pragma unroll
    for (int ob = 0; ob < 8; ++ob) s += part1[ob * 1024 + k];
    u1g[k] = s;
}

// bc = sF[15] + mb1·u1
__global__ void mlp_c(const void* __restrict__ mb1, const float* __restrict__ u1g,
                      float* __restrict__ sF, const int* __restrict__ fdt)
{
    __shared__ float red[4];
    int t = threadIdx.x;
    const int f32 = fdt[0];
    float p = 0.f;
    for (int k = t; k < 1024; k += 256) p += ldf(mb1, k, f32) * u1g[k];
    for (int o = 32; o; o >>= 1) p += __shfl_down(p, o);
    if ((t & 63) == 0) red[t >> 6] = p;
    __syncthreads();
    if (t == 0) sF[14] = sF[15] + red[0] + red[1] + red[2] + red[3];
}

// u0 stage1: grid (8, 16); part0[ob][k] over o-chunks of 64
__global__ void mlp_u0s1(const void* __restrict__ mW1, const float* __restrict__ u1g,
                         float* __restrict__ part0, const int* __restrict__ fdt)
{
    int k = blockIdx.x * 256 + threadIdx.x;
    if (k >= 1802) return;
    int o0 = blockIdx.y * 64;
    const int f32 = fdt[0];
    float s = 0.f;
#pragma unroll
    for (int oi = 0; oi < 64; ++oi) s += ldf(mW1, (long)(o0 + oi) * 1802 + k, f32) * u1g[o0 + oi];
    part0[blockIdx.y * 2048 + k] = s;
}

// u0 stage2: grid 8
__global__ void mlp_u0s2(const float* __restrict__ part0, float* __restrict__ u0)
{
    int k = blockIdx.x * 256 + threadIdx.x;
    if (k >= 1802) return;
    float s = 0.f;
#pragma unroll
    for (int ob = 0; ob < 16; ++ob) s += part0[ob * 2048 + k];
    u0[k] = s;
}

__global__ void rowdot(const float* __restrict__ sumx, const float* __restrict__ u0,
                       float* __restrict__ f, float* __restrict__ g)
{
    int r = blockIdx.x, t = threadIdx.x;
    float fa = 0.f, ga = 0.f;
    for (int o = t; o < OUTF; o += 256) {
        float v = sumx[(long)r * OUTF + o];
        fa += v * u0[o];
        ga += v * u0[OUTF + o];
    }
    for (int o = 32; o; o >>= 1) { fa += __shfl_down(fa, o); ga += __shfl_down(ga, o); }
    __shared__ float s[4][2];
    int lane = t & 63, wv = t >> 6;
    if (!lane) { s[wv][0] = fa; s[wv][1] = ga; }
    __syncthreads();
    if (t == 0) {
        f[r] = s[0][0] + s[1][0] + s[2][0] + s[3][0];
        g[r] = s[0][1] + s[1][1] + s[2][1] + s[3][1];
    }
}

__global__ void score(const int* __restrict__ ts, const float* __restrict__ f,
                      const float* __restrict__ g, const float* __restrict__ sF,
                      void* __restrict__ out, const int* __restrict__ fdt)
{
    int p = blockIdx.x * 256 + threadIdx.x;
    if (p >= 4096) return;
    float v = sane(f[ts[2 * p]] + g[ts[2 * p + 1]] + sF[14]);
    if (fdt[0]) ((float*)out)[p] = v;
    else        ((__hip_bfloat16*)out)[p] = f2b(v);
}

// ---------------- launch ----------------
extern "C" void kernel_launch(void* const* d_in, const int* in_sizes, int n_in,
                              void* d_out, int out_size, void* d_ws, size_t ws_size,
                              hipStream_t stream)
{
    const int NVv[3]   = {2060, 2459, 3929};
    const int NVPv[3]  = {2176, 2560, 3968};
    const int IOFFv[3] = {282, 681, 2151};
    const int ADJ_I[3] = {0, 1, 2}, FEAT_I[3] = {4, 5, 6}, W_I[3] = {8, 12, 16},
              AS_I[3] = {9, 13, 17}, AD_I[3] = {10, 14, 18}, BV_I[3] = {11, 15, 19};

    char* w = (char*)d_ws;
    size_t off = 0;
    auto alloc = [&](size_t b) { void* p = w + off; off += (b + 255) & ~(size_t)255; return p; };

    ushort* hT   = (ushort*)alloc(1024ULL * 3968 * 2);            // 8.1 MB
    ushort* Pexp = (ushort*)alloc(1792ULL * 3968 * 2);            // 14.2 MB
    __hip_bfloat16* voutb[3];
    for (int v = 0; v < 3; ++v)
        voutb[v] = (__hip_bfloat16*)alloc((size_t)NROWS * OUTF * 2);  // 3x 3.2 MB
    float*  asrc   = (float*)alloc(3968 * 4);
    float*  adst   = (float*)alloc(3968 * 4);
    float*  lrow   = (float*)alloc(1792 * 4);
    double* statsD = (double*)alloc(8 * 8);
    float*  statsF = (float*)alloc(16 * 4);
    float*  u3g    = (float*)alloc(64 * 4);
    float*  u2g    = (float*)alloc(512 * 4);
    float*  u1     = (float*)alloc(1024 * 4);
    float*  u0     = (float*)alloc(1802 * 4);
    float*  part1  = (float*)alloc(8 * 1024 * 4);
    float*  part0  = (float*)alloc(16 * 2048 * 4);
    float*  fv     = (float*)alloc(NROWS * 4);
    float*  gv     = (float*)alloc(NROWS * 4);
    int*    fdt    = (int*)alloc(4);
    // fast-path-only: featPad allocated last so the compact set fits small ws
    ushort* featPad = (ushort*)alloc(3968ULL * 3968 * 2);         // 31.5 MB
    const bool use_fast = (ws_size >= off);
    // overlays on dead regions
    ushort* Wpad = Pexp;            // Wpad (8.1 MB) lives in Pexp (14.2 MB) during gemm1
    float*  sumx = (float*)hT;      // hT dead after view loop; sumx 6.4 MB < 8.1 MB

    probe_dtype<<<1, 256, 0, stream>>>((const ushort*)d_in[9], fdt);

    for (int v = 0; v < 3; ++v) {
        int Nv = NVv[v], Nvp = NVPv[v], ioff2 = IOFFv[v];
        int Kp = (Nv + 63) & ~63;

        dim3 gg1(Nvp / 128, 8);   // hT[1024, Nvp] = W · feat^T
        if (use_fast) {
            dim3 gpk((Nvp + 255) / 256, Nvp);
            pack_dual<<<gpk, 256, 0, stream>>>((__hip_bfloat16*)featPad, d_in[FEAT_I[v]],
                                               Nv, Nv, Nv, Nvp, fdt);
            dim3 gpw((Nvp + 255) / 256, 1024);
            pack_dual<<<gpw, 256, 0, stream>>>((__hip_bfloat16*)Wpad, d_in[W_I[v]],
                                               901, Nv, Nv, Nvp, fdt);
            gemm_fast<0><<<gg1, 256, 0, stream>>>(Wpad, featPad, Nvp,
                (__hip_bfloat16*)hT, Nvp, nullptr, nullptr, nullptr, 0, 0, fdt);
        } else {
            gemm1_raw<<<gg1, 256, 0, stream>>>(d_in[W_I[v]], d_in[FEAT_I[v]], Kp,
                                               Nv, Nv, 901, Nv, Nv,
                                               (__hip_bfloat16*)hT, Nvp, fdt);
        }

        srcdst<<<(Nv + 255) / 256, 256, 0, stream>>>((const __hip_bfloat16*)hT,
            d_in[AS_I[v]], d_in[AD_I[v]], Nv, Nvp, asrc, adst, fdt);

        zerof<<<7, 256, 0, stream>>>(lrow, 1792);
        dim3 gp(Nvp / 64, 28);
        pbuild<<<gp, 256, 0, stream>>>((const int*)d_in[ADJ_I[v]], asrc, adst, Nv, Nvp, ioff2,
                                       (__hip_bfloat16*)Pexp, lrow);

        dim3 gg2(8, 14);          // vout[1778,901] = relu(P·h / l + b)
        gemm_fast<1><<<gg2, 256, 0, stream>>>(Pexp, hT, Nvp,
            nullptr, 0, lrow, d_in[BV_I[v]], voutb[v], NROWS, OUTF, fdt);
    }

    zerof<<<1, 256, 0, stream>>>((float*)statsD, 16);
    int gb = (NEL + 255) / 256;
    cam_pass1<<<gb, 256, 0, stream>>>(voutb[0], voutb[1], voutb[2], d_in[7],
        d_in[20], d_in[21], d_in[24], d_in[25], statsD, fdt);
    cam_fin1<<<1, 64, 0, stream>>>(statsD, statsF);
    cam_pass2<<<gb, 256, 0, stream>>>(voutb[0], voutb[1], voutb[2], d_in[7],
        d_in[20], d_in[21], d_in[24], d_in[25], statsF, statsD, fdt);
    cam_fin2<<<1, 64, 0, stream>>>(statsD, statsF, d_in[22], d_in[26], fdt);
    cam_fuse<<<gb, 256, 0, stream>>>(voutb[0], voutb[1], voutb[2], d_in[7],
        d_in[20], d_in[21], d_in[24], d_in[25], statsF, sumx, fdt);

    // collapsed MLP head, parallelized
    mlp_a<<<1, 256, 0, stream>>>(d_in[32], d_in[34], d_in[31], d_in[33], d_in[35],
                                 u3g, u2g, statsF, fdt);
    mlp_b1<<<dim3(4, 8), 256, 0, stream>>>(d_in[30], u2g, part1, fdt);
    mlp_b2<<<4, 256, 0, stream>>>(part1, u1);
    mlp_c<<<1, 256, 0, stream>>>(d_in[29], u1, statsF, fdt);
    mlp_u0s1<<<dim3(8, 16), 256, 0, stream>>>(d_in[28], u1, part0, fdt);
    mlp_u0s2<<<8, 256, 0, stream>>>(part0, u0);

    rowdot<<<NROWS, 256, 0, stream>>>(sumx, u0, fv, gv);
    score<<<16, 256, 0, stream>>>((const int*)d_in[3], fv, gv, statsF, d_out, fdt);
}

// Round 7
// 1146.076 us; speedup vs baseline: 2.9553x; 1.2621x over previous
//
#include <hip/hip_runtime.h>
#include <hip/hip_bf16.h>
#include <stdint.h>

typedef __attribute__((ext_vector_type(8))) short short8;
typedef __attribute__((ext_vector_type(4))) float f32x4;

#define AS1 __attribute__((address_space(1)))
#define AS3 __attribute__((address_space(3)))

#define NEL 1601978   // 1778*901
#define NROWS 1778
#define OUTF 901

__device__ __forceinline__ float b2f(__hip_bfloat16 x) { return __bfloat162float(x); }
__device__ __forceinline__ __hip_bfloat16 f2b(float x) { return __float2bfloat16(x); }
__device__ __forceinline__ float sane(float v) { return isfinite(v) ? v : 0.f; }

// dtype-dual load: flag==1 -> fp32 array, flag==0 -> bf16 array
__device__ __forceinline__ float ldf(const void* p, long i, int f32)
{
    return f32 ? ((const float*)p)[i] : b2f(((const __hip_bfloat16*)p)[i]);
}

// ---------------- dtype probe ----------------
__global__ void probe_dtype(const ushort* __restrict__ p, int* __restrict__ fdt)
{
    int t = threadIdx.x;
    int cnt = 0;
    for (int i = t; i < 512; i += 256) {
        int ex = (p[i] >> 7) & 0xFF;
        if (ex >= 0x85) cnt++;
    }
    for (int o = 32; o; o >>= 1) cnt += __shfl_down(cnt, o);
    __shared__ int s[4];
    if ((t & 63) == 0) s[t >> 6] = cnt;
    __syncthreads();
    if (t == 0) fdt[0] = (s[0] + s[1] + s[2] + s[3] > 16) ? 1 : 0;
}

// ---------------- zero scratch ----------------
__global__ void zerof(float* __restrict__ p, int n)
{
    int i = blockIdx.x * 256 + threadIdx.x;
    if (i < n) p[i] = 0.f;
}

// ---------------- pack (fp32|bf16) -> padded bf16 ----------------
__global__ void pack_dual(__hip_bfloat16* __restrict__ dst, const void* __restrict__ src,
                          int rows_valid, int cols_valid, int src_ld, int dst_ld,
                          const int* __restrict__ fdt)
{
    int c = blockIdx.x * 256 + threadIdx.x;
    int r = blockIdx.y;
    if (c >= dst_ld) return;
    float v = 0.f;
    if (r < rows_valid && c < cols_valid) v = ldf(src, (long)r * src_ld + c, fdt[0]);
    dst[(long)r * dst_ld + c] = f2b(v);
}

// ---------------- vector-staged bf16 GEMM: C = A(M,K) * B(N,K)^T ----------------
// A,B padded (stride K, rows cover the full grid), K*2 bytes 16B-aligned.
// Staging: global_load_lds width 16 (async direct-to-LDS, m97 pattern).
// EPI 0: store bf16 C[m*ldc+n].  EPI 1: relu(C/l[m] + bias[n]) -> bf16 vout.
template<int EPI>
__global__ __launch_bounds__(256)
void gemm_fast(const ushort* __restrict__ A, const ushort* __restrict__ B, int K,
               __hip_bfloat16* __restrict__ Cbf, int ldc,
               const float* __restrict__ lrow, const void* __restrict__ bias,
               __hip_bfloat16* __restrict__ vout, int Mvalid, int Nvalid,
               const int* __restrict__ fdt)
{
    __shared__ __align__(16) ushort sA[128 * 64];
    __shared__ __align__(16) ushort sB[128 * 64];
    const int tid = threadIdx.x;
    const int lane = tid & 63;
    const int wid = tid >> 6;
    const int wm = (wid >> 1) * 64;
    const int wn = (wid & 1) * 64;
    const long m0 = (long)blockIdx.y * 128;
    const long n0 = (long)blockIdx.x * 128;

    f32x4 acc[4][4];
#pragma unroll
    for (int i = 0; i < 4; ++i)
#pragma unroll
        for (int j = 0; j < 4; ++j) acc[i][j] = (f32x4){0.f, 0.f, 0.f, 0.f};

    const int rsub = lane >> 3;       // 0..7 row within 8-row slab
    const int csub = (lane & 7) * 8;  // element col offset; lane LDS off = lane*16B
    const int koff = (lane >> 4) * 8;
    const int rowf = lane & 15;

    for (int k0 = 0; k0 < K; k0 += 64) {
        __syncthreads();
#pragma unroll
        for (int it = 0; it < 4; ++it) {
            int rb = wid * 32 + it * 8;
            int r = rb + rsub;
            __builtin_amdgcn_global_load_lds(
                (const AS1 uint*)(const void*)(A + (m0 + r) * (long)K + k0 + csub),
                (AS3 uint*)&sA[r * 64 + csub], 16, 0, 0);
            __builtin_amdgcn_global_load_lds(
                (const AS1 uint*)(const void*)(B + (n0 + r) * (long)K + k0 + csub),
                (AS3 uint*)&sB[r * 64 + csub], 16, 0, 0);
        }
        __syncthreads();   // drains vmcnt(0): LDS-direct loads complete
#pragma unroll
        for (int ks = 0; ks < 64; ks += 32) {
            short8 af[4], bfr[4];
            int kb = ks + koff;
#pragma unroll
            for (int f = 0; f < 4; ++f) {
                af[f]  = *(const short8*)(&sA[(wm + f * 16 + rowf) * 64 + kb]);
                bfr[f] = *(const short8*)(&sB[(wn + f * 16 + rowf) * 64 + kb]);
            }
#pragma unroll
            for (int i = 0; i < 4; ++i)
#pragma unroll
                for (int j = 0; j < 4; ++j)
                    acc[i][j] = __builtin_amdgcn_mfma_f32_16x16x32_bf16(af[i], bfr[j], acc[i][j], 0, 0, 0);
        }
    }

    const int f32 = (EPI == 1) ? fdt[0] : 0;
    const int rq = (lane >> 4) * 4;   // C/D: col = lane&15, row = (lane>>4)*4 + reg
#pragma unroll
    for (int i = 0; i < 4; ++i)
#pragma unroll
        for (int j = 0; j < 4; ++j)
#pragma unroll
            for (int rg = 0; rg < 4; ++rg) {
                long m = m0 + wm + i * 16 + rq + rg;
                long n = n0 + wn + j * 16 + (lane & 15);
                float v = acc[i][j][rg];
                if constexpr (EPI == 0) {
                    Cbf[m * ldc + n] = f2b(v);
                } else {
                    if (m < Mvalid && n < Nvalid) {
                        float den = fmaxf(lrow[m], 1e-30f);
                        float r = v / den + ldf(bias, n, f32);
                        vout[m * Nvalid + n] = f2b(sane(fmaxf(r, 0.f)));
                    }
                }
            }
}

// ---------------- GEMM1 fallback: raw operands, dtype-dual scalar staging ----------------
__global__ __launch_bounds__(256)
void gemm1_raw(const void* __restrict__ A, const void* __restrict__ B, int K,
               int lda, int ldb, int Ma, int Nb, int Kv,
               __hip_bfloat16* __restrict__ Cbf, int ldc, const int* __restrict__ fdt)
{
    __shared__ __align__(16) ushort sA[128 * 64];
    __shared__ __align__(16) ushort sB[128 * 64];
    const int f32 = fdt[0];
    const int tid = threadIdx.x;
    const int lane = tid & 63;
    const int wid = tid >> 6;
    const int wm = (wid >> 1) * 64;
    const int wn = (wid & 1) * 64;
    const long m0 = (long)blockIdx.y * 128;
    const long n0 = (long)blockIdx.x * 128;

    f32x4 acc[4][4];
#pragma unroll
    for (int i = 0; i < 4; ++i)
#pragma unroll
        for (int j = 0; j < 4; ++j) acc[i][j] = (f32x4){0.f, 0.f, 0.f, 0.f};

    const int lr = tid >> 3;
    const int lc = (tid & 7) * 8;
    const int koff = (lane >> 4) * 8;
    const int rowf = lane & 15;

    for (int k0 = 0; k0 < K; k0 += 64) {
        __syncthreads();
#pragma unroll
        for (int it = 0; it < 4; ++it) {
            int r = it * 32 + lr;
            long gm = m0 + r, gn = n0 + r;
            ushort va[8], vb[8];
#pragma unroll
            for (int e = 0; e < 8; ++e) {
                int k = k0 + lc + e;
                bool kok = (k < Kv);
                float fa = (kok && gm < Ma) ? ldf(A, gm * (long)lda + k, f32) : 0.f;
                float fb = (kok && gn < Nb) ? ldf(B, gn * (long)ldb + k, f32) : 0.f;
                va[e] = __hip_bfloat16_raw(f2b(fa)).x;
                vb[e] = __hip_bfloat16_raw(f2b(fb)).x;
            }
#pragma unroll
            for (int e = 0; e < 8; ++e) { sA[r * 64 + lc + e] = va[e]; sB[r * 64 + lc + e] = vb[e]; }
        }
        __syncthreads();
#pragma unroll
        for (int ks = 0; ks < 64; ks += 32) {
            short8 af[4], bfr[4];
            int kb = ks + koff;
#pragma unroll
            for (int f = 0; f < 4; ++f) {
                af[f]  = *(const short8*)(&sA[(wm + f * 16 + rowf) * 64 + kb]);
                bfr[f] = *(const short8*)(&sB[(wn + f * 16 + rowf) * 64 + kb]);
            }
#pragma unroll
            for (int i = 0; i < 4; ++i)
#pragma unroll
                for (int j = 0; j < 4; ++j)
                    acc[i][j] = __builtin_amdgcn_mfma_f32_16x16x32_bf16(af[i], bfr[j], acc[i][j], 0, 0, 0);
        }
    }

    const int rq = (lane >> 4) * 4;
#pragma unroll
    for (int i = 0; i < 4; ++i)
#pragma unroll
        for (int j = 0; j < 4; ++j)
#pragma unroll
            for (int rg = 0; rg < 4; ++rg) {
                long m = m0 + wm + i * 16 + rq + rg;
                long n = n0 + wn + j * 16 + (lane & 15);
                Cbf[m * ldc + n] = f2b(acc[i][j][rg]);
            }
}

// ---------------- asrc/adst: parallel over (j, o-chunks), atomic accumulate ----------------
// grid (ceil(Nv/256), 8); asrc/adst must be pre-zeroed.
__global__ void srcdst2(const __hip_bfloat16* __restrict__ hT,
                        const void* __restrict__ a_src, const void* __restrict__ a_dst,
                        int Nv, int Nvp, float* __restrict__ asrc, float* __restrict__ adst,
                        const int* __restrict__ fdt)
{
    const int f32 = fdt[0];
    int j = blockIdx.x * 256 + threadIdx.x;
    if (j >= Nv) return;
    int o0 = blockIdx.y * 113;
    int o1 = min(OUTF, o0 + 113);
    float s1 = 0.f, s2 = 0.f;
    for (int o = o0; o < o1; ++o) {
        float hv = b2f(hT[(long)o * Nvp + j]);
        s1 += hv * ldf(a_src, o, f32);
        s2 += hv * ldf(a_dst, o, f32);
    }
    atomicAdd(&asrc[j], s1);
    atomicAdd(&adst[j], s2);
}

// ---------------- P = mask * exp(leaky(adst_i + asrc_j)), row sums l ----------------
__global__ void pbuild(const int* __restrict__ adj, const float* __restrict__ asrc,
                       const float* __restrict__ adst, int Nv, int Nvp, int ioff,
                       __hip_bfloat16* __restrict__ P, float* __restrict__ l)
{
    const int lane = threadIdx.x & 63, grp = threadIdx.x >> 6;
    const int j0 = blockIdx.x * 64, r0 = blockIdx.y * 64;
    const int j = j0 + lane;
    const float as = (j < Nv) ? asrc[j] : 0.f;
#pragma unroll
    for (int it = 0; it < 16; ++it) {
        int rr = it * 4 + grp;
        int r = r0 + rr;
        int i = (r < 901) ? r : r + ioff;
        float p = 0.f;
        if (r < NROWS && j < Nv) {
            bool m = (adj[(long)j * Nv + i] != 0) || (i == j);
            if (m) {
                float e = adst[i] + as;
                e = e > 0.f ? e : 0.2f * e;
                p = expf(fminf(e, 30.f));
            }
        }
        __hip_bfloat16 pb = f2b(p);
        if (r < 1792) P[(long)r * Nvp + j] = pb;
        float pv = b2f(pb);
        for (int o = 32; o; o >>= 1) pv += __shfl_down(pv, o);
        if (lane == 0 && r < NROWS) atomicAdd(&l[r], pv);
    }
}

// ---------------- CAM ----------------
__device__ __forceinline__ void block_reduce_atomic4(float a, float b, float c, float d, double* out)
{
    for (int o = 32; o; o >>= 1) {
        a += __shfl_down(a, o); b += __shfl_down(b, o);
        c += __shfl_down(c, o); d += __shfl_down(d, o);
    }
    __shared__ float s[4][4];
    int lane = threadIdx.x & 63, wv = threadIdx.x >> 6;
    if (lane == 0) { s[wv][0] = a; s[wv][1] = b; s[wv][2] = c; s[wv][3] = d; }
    __syncthreads();
    if (threadIdx.x < 4) {
        float v = s[0][threadIdx.x] + s[1][threadIdx.x] + s[2][threadIdx.x] + s[3][threadIdx.x];
        atomicAdd(out + threadIdx.x, (double)v);
    }
}

__device__ __forceinline__ void camY(int idx,
    const __hip_bfloat16* v0, const __hip_bfloat16* v1, const __hip_bfloat16* v2,
    const void* md, const void* lw1, const void* lb1, const void* gw1, const void* gb1,
    int f32, float& Yl, float& Yg)
{
    float x0 = b2f(v0[idx]), x1 = b2f(v1[idx]), x2 = b2f(v2[idx]), x3 = ldf(md, idx, f32);
    Yl = ldf(lw1,0,f32)*x0 + ldf(lw1,1,f32)*x1 + ldf(lw1,2,f32)*x2 + ldf(lw1,3,f32)*x3 + ldf(lb1,0,f32);
    Yg = ldf(gw1,0,f32)*x0 + ldf(gw1,1,f32)*x1 + ldf(gw1,2,f32)*x2 + ldf(gw1,3,f32)*x3 + ldf(gb1,0,f32);
}

__global__ void cam_pass1(const __hip_bfloat16* __restrict__ v0, const __hip_bfloat16* __restrict__ v1,
                          const __hip_bfloat16* __restrict__ v2, const void* __restrict__ md,
                          const void* __restrict__ lw1, const void* __restrict__ lb1,
                          const void* __restrict__ gw1, const void* __restrict__ gb1,
                          double* __restrict__ sD, const int* __restrict__ fdt)
{
    int idx = blockIdx.x * 256 + threadIdx.x;
    float a = 0, b = 0, c = 0, d = 0;
    if (idx < NEL) {
        float Yl, Yg;
        camY(idx, v0, v1, v2, md, lw1, lb1, gw1, gb1, fdt[0], Yl, Yg);
        a = Yl; b = Yl * Yl; c = Yg; d = Yg * Yg;
    }
    block_reduce_atomic4(a, b, c, d, sD);
}

__global__ void cam_fin1(const double* __restrict__ sD, float* __restrict__ sF)
{
    if (threadIdx.x == 0) {
        double n = (double)NEL;
        double ml = sD[0] / n, vl = sD[1] / n - ml * ml;
        double mg = sD[2] / n, vg = sD[3] / n - mg * mg;
        if (vl < 0.0) vl = 0.0;
        if (vg < 0.0) vg = 0.0;
        sF[0] = (float)ml; sF[1] = (float)(1.0 / sqrt(vl + 1e-5));
        sF[2] = (float)mg; sF[3] = (float)(1.0 / sqrt(vg + 1e-5));
    }
}

__global__ void cam_pass2(const __hip_bfloat16* __restrict__ v0, const __hip_bfloat16* __restrict__ v1,
                          const __hip_bfloat16* __restrict__ v2, const void* __restrict__ md,
                          const void* __restrict__ lw1, const void* __restrict__ lb1,
                          const void* __restrict__ gw1, const void* __restrict__ gb1,
                          const float* __restrict__ sF, double* __restrict__ sD,
                          const int* __restrict__ fdt)
{
    int idx = blockIdx.x * 256 + threadIdx.x;
    float a = 0, b = 0, c = 0, d = 0;
    if (idx < NEL) {
        float Yl, Yg;
        camY(idx, v0, v1, v2, md, lw1, lb1, gw1, gb1, fdt[0], Yl, Yg);
        float zl = fmaxf((Yl - sF[0]) * sF[1], 0.f);
        float zg = fmaxf((Yg - sF[2]) * sF[3], 0.f);
        a = zl; b = zl * zl; c = zg; d = zg * zg;
    }
    block_reduce_atomic4(a, b, c, d, sD + 4);
}

__global__ void cam_fin2(const double* __restrict__ sD, float* __restrict__ sF,
                         const void* __restrict__ lw2, const void* __restrict__ gw2,
                         const int* __restrict__ fdt)
{
    if (threadIdx.x == 0) {
        const int f32 = fdt[0];
        double n = (double)NEL;
        double mzl = sD[4] / n, vzl = sD[5] / n - mzl * mzl;
        double mzg = sD[6] / n, vzg = sD[7] / n - mzg * mzg;
        if (vzl < 0.0) vzl = 0.0;
        if (vzg < 0.0) vzg = 0.0;
        sF[4] = (float)mzl; sF[5] = (float)mzg;
        for (int c = 0; c < 4; ++c) {
            double wl = (double)ldf(lw2, c, f32);
            double wg = (double)ldf(gw2, c, f32);
            sF[6 + c]  = (float)(wl / sqrt(wl * wl * vzl + 1e-5));
            sF[10 + c] = (float)(wg / sqrt(wg * wg * vzg + 1e-5));
        }
    }
}

__global__ void cam_fuse(const __hip_bfloat16* __restrict__ v0, const __hip_bfloat16* __restrict__ v1,
                         const __hip_bfloat16* __restrict__ v2, const void* __restrict__ md,
                         const void* __restrict__ lw1, const void* __restrict__ lb1,
                         const void* __restrict__ gw1, const void* __restrict__ gb1,
                         const float* __restrict__ sF, float* __restrict__ sumx,
                         const int* __restrict__ fdt)
{
    int idx = blockIdx.x * 256 + threadIdx.x;
    if (idx >= NEL) return;
    const int f32 = fdt[0];
    float Yl, Yg;
    camY(idx, v0, v1, v2, md, lw1, lb1, gw1, gb1, f32, Yl, Yg);
    float zl = fmaxf((Yl - sF[0]) * sF[1], 0.f);
    float zg = fmaxf((Yg - sF[2]) * sF[3], 0.f);
    float dzl = zl - sF[4], dzg = zg - sF[5];
    float x[4] = {b2f(v0[idx]), b2f(v1[idx]), b2f(v2[idx]), ldf(md, idx, f32)};
    float s = 0.f;
#pragma unroll
    for (int c = 0; c < 4; ++c) {
        float t = sF[6 + c] * dzl + sF[10 + c] * dzg;
        s += x[c] / (1.f + expf(-t));
    }
    sumx[idx] = 0.25f * s;
}

// ---------------- collapsed MLP head (parallel, multi-kernel) ----------------
__global__ void mlp_a(const void* __restrict__ mW3, const void* __restrict__ mW4,
                      const void* __restrict__ mb2, const void* __restrict__ mb3,
                      const void* __restrict__ mb4,
                      float* __restrict__ u3g, float* __restrict__ u2g,
                      float* __restrict__ sF, const int* __restrict__ fdt)
{
    __shared__ float u3[64];
    __shared__ float red[4];
    const int f32 = fdt[0];
    int t = threadIdx.x;
    if (t < 64) { float v = ldf(mW4, t, f32); u3[t] = v; u3g[t] = v; }
    __syncthreads();
    float part = 0.f;
    for (int k = t; k < 512; k += 256) {
        float s = 0.f;
#pragma unroll
        for (int o = 0; o < 64; ++o) s += ldf(mW3, o * 512 + k, f32) * u3[o];
        u2g[k] = s;
        part += ldf(mb2, k, f32) * s;
    }
    if (t < 64) part += ldf(mb3, t, f32) * u3[t];
    for (int o = 32; o; o >>= 1) part += __shfl_down(part, o);
    if ((t & 63) == 0) red[t >> 6] = part;
    __syncthreads();
    if (t == 0) sF[15] = red[0] + red[1] + red[2] + red[3] + ldf(mb4, 0, f32);
}

__global__ void mlp_b1(const void* __restrict__ mW2, const float* __restrict__ u2g,
                       float* __restrict__ part1, const int* __restrict__ fdt)
{
    int k = blockIdx.x * 256 + threadIdx.x;
    int o0 = blockIdx.y * 64;
    const int f32 = fdt[0];
    float s = 0.f;
#pragma unroll
    for (int oi = 0; oi < 64; ++oi) s += ldf(mW2, (long)(o0 + oi) * 1024 + k, f32) * u2g[o0 + oi];
    part1[blockIdx.y * 1024 + k] = s;
}

__global__ void mlp_b2(const float* __restrict__ part1, float* __restrict__ u1g)
{
    int k = blockIdx.x * 256 + threadIdx.x;
    float s = 0.f;
#pragma unroll
    for (int ob = 0; ob < 8; ++ob) s += part1[ob * 1024 + k];
    u1g[k] = s;
}

__global__ void mlp_c(const void* __restrict__ mb1, const float* __restrict__ u1g,
                      float* __restrict__ sF, const int* __restrict__ fdt)
{
    __shared__ float red[4];
    int t = threadIdx.x;
    const int f32 = fdt[0];
    float p = 0.f;
    for (int k = t; k < 1024; k += 256) p += ldf(mb1, k, f32) * u1g[k];
    for (int o = 32; o; o >>= 1) p += __shfl_down(p, o);
    if ((t & 63) == 0) red[t >> 6] = p;
    __syncthreads();
    if (t == 0) sF[14] = sF[15] + red[0] + red[1] + red[2] + red[3];
}

__global__ void mlp_u0s1(const void* __restrict__ mW1, const float* __restrict__ u1g,
                         float* __restrict__ part0, const int* __restrict__ fdt)
{
    int k = blockIdx.x * 256 + threadIdx.x;
    if (k >= 1802) return;
    int o0 = blockIdx.y * 64;
    const int f32 = fdt[0];
    float s = 0.f;
#pragma unroll
    for (int oi = 0; oi < 64; ++oi) s += ldf(mW1, (long)(o0 + oi) * 1802 + k, f32) * u1g[o0 + oi];
    part0[blockIdx.y * 2048 + k] = s;
}

__global__ void mlp_u0s2(const float* __restrict__ part0, float* __restrict__ u0)
{
    int k = blockIdx.x * 256 + threadIdx.x;
    if (k >= 1802) return;
    float s = 0.f;
#pragma unroll
    for (int ob = 0; ob < 16; ++ob) s += part0[ob * 2048 + k];
    u0[k] = s;
}

__global__ void rowdot(const float* __restrict__ sumx, const float* __restrict__ u0,
                       float* __restrict__ f, float* __restrict__ g)
{
    int r = blockIdx.x, t = threadIdx.x;
    float fa = 0.f, ga = 0.f;
    for (int o = t; o < OUTF; o += 256) {
        float v = sumx[(long)r * OUTF + o];
        fa += v * u0[o];
        ga += v * u0[OUTF + o];
    }
    for (int o = 32; o; o >>= 1) { fa += __shfl_down(fa, o); ga += __shfl_down(ga, o); }
    __shared__ float s[4][2];
    int lane = t & 63, wv = t >> 6;
    if (!lane) { s[wv][0] = fa; s[wv][1] = ga; }
    __syncthreads();
    if (t == 0) {
        f[r] = s[0][0] + s[1][0] + s[2][0] + s[3][0];
        g[r] = s[0][1] + s[1][1] + s[2][1] + s[3][1];
    }
}

__global__ void score(const int* __restrict__ ts, const float* __restrict__ f,
                      const float* __restrict__ g, const float* __restrict__ sF,
                      void* __restrict__ out, const int* __restrict__ fdt)
{
    int p = blockIdx.x * 256 + threadIdx.x;
    if (p >= 4096) return;
    float v = sane(f[ts[2 * p]] + g[ts[2 * p + 1]] + sF[14]);
    if (fdt[0]) ((float*)out)[p] = v;
    else        ((__hip_bfloat16*)out)[p] = f2b(v);
}

// ---------------- launch ----------------
extern "C" void kernel_launch(void* const* d_in, const int* in_sizes, int n_in,
                              void* d_out, int out_size, void* d_ws, size_t ws_size,
                              hipStream_t stream)
{
    const int NVv[3]   = {2060, 2459, 3929};
    const int NVPv[3]  = {2176, 2560, 3968};
    const int IOFFv[3] = {282, 681, 2151};
    const int ADJ_I[3] = {0, 1, 2}, FEAT_I[3] = {4, 5, 6}, W_I[3] = {8, 12, 16},
              AS_I[3] = {9, 13, 17}, AD_I[3] = {10, 14, 18}, BV_I[3] = {11, 15, 19};

    char* w = (char*)d_ws;
    size_t off = 0;
    auto alloc = [&](size_t b) { void* p = w + off; off += (b + 255) & ~(size_t)255; return p; };

    ushort* hT   = (ushort*)alloc(1024ULL * 3968 * 2);            // 8.1 MB
    ushort* Pexp = (ushort*)alloc(1792ULL * 3968 * 2);            // 14.2 MB
    __hip_bfloat16* voutb[3];
    for (int v = 0; v < 3; ++v)
        voutb[v] = (__hip_bfloat16*)alloc((size_t)NROWS * OUTF * 2);  // 3x 3.2 MB
    // asrc/adst/lrow contiguous (each size multiple of 256B) -> single zerof
    float*  asrc   = (float*)alloc(3968 * 4);
    float*  adst   = (float*)alloc(3968 * 4);
    float*  lrow   = (float*)alloc(1792 * 4);
    double* statsD = (double*)alloc(8 * 8);
    float*  statsF = (float*)alloc(16 * 4);
    float*  u3g    = (float*)alloc(64 * 4);
    float*  u2g    = (float*)alloc(512 * 4);
    float*  u1     = (float*)alloc(1024 * 4);
    float*  u0     = (float*)alloc(1802 * 4);
    float*  part1  = (float*)alloc(8 * 1024 * 4);
    float*  part0  = (float*)alloc(16 * 2048 * 4);
    float*  fv     = (float*)alloc(NROWS * 4);
    float*  gv     = (float*)alloc(NROWS * 4);
    int*    fdt    = (int*)alloc(4);
    // fast-path-only: featPad allocated last so the compact set fits small ws
    ushort* featPad = (ushort*)alloc(3968ULL * 3968 * 2);         // 31.5 MB
    const bool use_fast = (ws_size >= off);
    // overlays on dead regions
    ushort* Wpad = Pexp;            // Wpad (8.1 MB) lives in Pexp (14.2 MB) during gemm1
    float*  sumx = (float*)hT;      // hT dead after view loop; sumx 6.4 MB < 8.1 MB

    probe_dtype<<<1, 256, 0, stream>>>((const ushort*)d_in[9], fdt);

    for (int v = 0; v < 3; ++v) {
        int Nv = NVv[v], Nvp = NVPv[v], ioff2 = IOFFv[v];
        int Kp = (Nv + 63) & ~63;

        dim3 gg1(Nvp / 128, 8);   // hT[1024, Nvp] = W · feat^T
        if (use_fast) {
            dim3 gpk((Nvp + 255) / 256, Nvp);
            pack_dual<<<gpk, 256, 0, stream>>>((__hip_bfloat16*)featPad, d_in[FEAT_I[v]],
                                               Nv, Nv, Nv, Nvp, fdt);
            dim3 gpw((Nvp + 255) / 256, 1024);
            pack_dual<<<gpw, 256, 0, stream>>>((__hip_bfloat16*)Wpad, d_in[W_I[v]],
                                               901, Nv, Nv, Nvp, fdt);
            gemm_fast<0><<<gg1, 256, 0, stream>>>(Wpad, featPad, Nvp,
                (__hip_bfloat16*)hT, Nvp, nullptr, nullptr, nullptr, 0, 0, fdt);
        } else {
            gemm1_raw<<<gg1, 256, 0, stream>>>(d_in[W_I[v]], d_in[FEAT_I[v]], Kp,
                                               Nv, Nv, 901, Nv, Nv,
                                               (__hip_bfloat16*)hT, Nvp, fdt);
        }

        // zero asrc+adst+lrow in one shot (contiguous: 3968+3968+1792 floats)
        zerof<<<38, 256, 0, stream>>>(asrc, 3968 + 3968 + 1792);

        dim3 gsd((Nv + 255) / 256, 8);
        srcdst2<<<gsd, 256, 0, stream>>>((const __hip_bfloat16*)hT,
            d_in[AS_I[v]], d_in[AD_I[v]], Nv, Nvp, asrc, adst, fdt);

        dim3 gp(Nvp / 64, 28);
        pbuild<<<gp, 256, 0, stream>>>((const int*)d_in[ADJ_I[v]], asrc, adst, Nv, Nvp, ioff2,
                                       (__hip_bfloat16*)Pexp, lrow);

        dim3 gg2(8, 14);          // vout[1778,901] = relu(P·h / l + b)
        gemm_fast<1><<<gg2, 256, 0, stream>>>(Pexp, hT, Nvp,
            nullptr, 0, lrow, d_in[BV_I[v]], voutb[v], NROWS, OUTF, fdt);
    }

    zerof<<<1, 256, 0, stream>>>((float*)statsD, 16);
    int gb = (NEL + 255) / 256;
    cam_pass1<<<gb, 256, 0, stream>>>(voutb[0], voutb[1], voutb[2], d_in[7],
        d_in[20], d_in[21], d_in[24], d_in[25], statsD, fdt);
    cam_fin1<<<1, 64, 0, stream>>>(statsD, statsF);
    cam_pass2<<<gb, 256, 0, stream>>>(voutb[0], voutb[1], voutb[2], d_in[7],
        d_in[20], d_in[21], d_in[24], d_in[25], statsF, statsD, fdt);
    cam_fin2<<<1, 64, 0, stream>>>(statsD, statsF, d_in[22], d_in[26], fdt);
    cam_fuse<<<gb, 256, 0, stream>>>(voutb[0], voutb[1], voutb[2], d_in[7],
        d_in[20], d_in[21], d_in[24], d_in[25], statsF, sumx, fdt);

    // collapsed MLP head, parallelized
    mlp_a<<<1, 256, 0, stream>>>(d_in[32], d_in[34], d_in[31], d_in[33], d_in[35],
                                 u3g, u2g, statsF, fdt);
    mlp_b1<<<dim3(4, 8), 256, 0, stream>>>(d_in[30], u2g, part1, fdt);
    mlp_b2<<<4, 256, 0, stream>>>(part1, u1);
    mlp_c<<<1, 256, 0, stream>>>(d_in[29], u1, statsF, fdt);
    mlp_u0s1<<<dim3(8, 16), 256, 0, stream>>>(d_in[28], u1, part0, fdt);
    mlp_u0s2<<<8, 256, 0, stream>>>(part0, u0);

    rowdot<<<NROWS, 256, 0, stream>>>(sumx, u0, fv, gv);
    score<<<16, 256, 0, stream>>>((const int*)d_in[3], fv, gv, statsF, d_out, fdt);
}